// Round 2
// baseline (664.185 us; speedup 1.0000x reference)
//
#include <hip/hip_runtime.h>
#include <hip/hip_bf16.h>
#include <stdint.h>

#define SEQ 4096
#define DIM 2048
#define NH 16
#define NKV 4
#define HD 128
#define KVLD 1024   /* K|V fused row stride in KVb */

// External I/O is FP32 (proven round 2/6); internal tensors bf16.

using frag8 = __attribute__((ext_vector_type(8))) short;
using f32x4 = __attribute__((ext_vector_type(4))) float;

union VecU { ushort u[8]; uint4 v; };

__device__ __forceinline__ float bf2f(ushort u) {
    union { uint32_t u; float f; } v; v.u = ((uint32_t)u) << 16; return v.f;
}
__device__ __forceinline__ ushort f2bf(float f) {
    union { float f; uint32_t u; } v; v.f = f;
    uint32_t r = v.u + 0x7fffu + ((v.u >> 16) & 1u);
    return (ushort)(r >> 16);
}

__device__ __forceinline__ void glds16(const void* g, void* l) {
    __builtin_amdgcn_global_load_lds(
        (const __attribute__((address_space(1))) void*)g,
        (__attribute__((address_space(3))) void*)l, 16, 0, 0);
}

// ---------------------------------------------------------------------------
// fp32 -> bf16 flat convert (8 elems/thread).
// ---------------------------------------------------------------------------
__global__ __launch_bounds__(256) void cvt_kernel(
    const float* __restrict__ src, ushort* __restrict__ dst)
{
    size_t i = ((size_t)blockIdx.x * 256 + threadIdx.x) * 8;
    float4 f0 = *(const float4*)&src[i];
    float4 f1 = *(const float4*)&src[i + 4];
    VecU t;
    t.u[0] = f2bf(f0.x); t.u[1] = f2bf(f0.y); t.u[2] = f2bf(f0.z); t.u[3] = f2bf(f0.w);
    t.u[4] = f2bf(f1.x); t.u[5] = f2bf(f1.y); t.u[6] = f2bf(f1.z); t.u[7] = f2bf(f1.w);
    *(uint4*)&dst[i] = t.v;
}

// ---------------------------------------------------------------------------
// fp32 [K][N] -> bf16 transposed [N][K], 32x32 tiles.
// ---------------------------------------------------------------------------
__global__ __launch_bounds__(256) void convT_kernel(
    const float* __restrict__ src, ushort* __restrict__ dst, int K, int N)
{
    __shared__ ushort T[32][36];
    int r  = threadIdx.x >> 3;
    int c4 = (threadIdx.x & 7) * 4;
    int bk = blockIdx.y * 32, bn = blockIdx.x * 32;
    float4 v = *(const float4*)&src[(size_t)(bk + r) * N + bn + c4];
    T[r][c4]     = f2bf(v.x); T[r][c4 + 1] = f2bf(v.y);
    T[r][c4 + 2] = f2bf(v.z); T[r][c4 + 3] = f2bf(v.w);
    __syncthreads();
    ushort4 o;
    o.x = T[c4][r]; o.y = T[c4 + 1][r]; o.z = T[c4 + 2][r]; o.w = T[c4 + 3][r];
    *(ushort4*)&dst[(size_t)(bn + r) * K + bk + c4] = o;
}

// ---------------------------------------------------------------------------
// bf16 V transpose: KVb[t][512 + d] (ld KVLD) -> VT[d][t] (ld SEQ), 32x32.
// ---------------------------------------------------------------------------
__global__ __launch_bounds__(256) void vtrans_kernel(
    const ushort* __restrict__ src, ushort* __restrict__ dst)
{
    __shared__ ushort T[32][36];
    int r  = threadIdx.x >> 3;
    int c4 = (threadIdx.x & 7) * 4;
    int bt = blockIdx.y * 32, bd = blockIdx.x * 32;   // t-block, d-block
    ushort4 v = *(const ushort4*)&src[(size_t)(bt + r) * KVLD + 512 + bd + c4];
    T[r][c4] = v.x; T[r][c4 + 1] = v.y; T[r][c4 + 2] = v.z; T[r][c4 + 3] = v.w;
    __syncthreads();
    ushort4 o;
    o.x = T[c4][r]; o.y = T[c4 + 1][r]; o.z = T[c4 + 2][r]; o.w = T[c4 + 3][r];
    *(ushort4*)&dst[(size_t)(bd + r) * SEQ + bt + c4] = o;
}

// ---------------------------------------------------------------------------
// m97-style GEMM: C[M][N] = A[M][K] @ BT[N][K]^T, bf16 in; CF: fp32/bf16 out.
// 128x128 tile, BK=32, global_load_lds(16B).
// ---------------------------------------------------------------------------
template <int CF>
__global__ __launch_bounds__(256) void gemm_tn(
    const ushort* __restrict__ A, const ushort* __restrict__ BT,
    void* __restrict__ C, int M, int N, int K)
{
    __shared__ ushort As[128 * 32];
    __shared__ ushort Bs[128 * 32];

    const int tid  = threadIdx.x;
    const int lane = tid & 63;
    const int wave = tid >> 6;
    const int bm   = blockIdx.y * 128;
    const int bn   = blockIdx.x * 128;
    const int wm   = (wave >> 1) * 64;
    const int wn   = (wave & 1) * 64;
    const int quad = lane >> 4;
    const int t16  = lane & 15;
    const int kg   = quad ^ ((t16 >> 1) & 3);

    f32x4 acc[4][4] = {};

    for (int k0 = 0; k0 < K; k0 += 32) {
        #pragma unroll
        for (int it = 0; it < 2; ++it) {
            int gid = it * 256 + tid;
            int r   = gid >> 2;
            int cs  = (gid & 3) ^ ((gid >> 3) & 3);
            glds16(&A[(size_t)(bm + r) * K + k0 + cs * 8],
                   &As[(it * 256 + wave * 64) * 8]);
            glds16(&BT[(size_t)(bn + r) * K + k0 + cs * 8],
                   &Bs[(it * 256 + wave * 64) * 8]);
        }
        __syncthreads();

        frag8 af[4], bf[4];
        #pragma unroll
        for (int i = 0; i < 4; ++i)
            af[i] = *(const frag8*)&As[(wm + i * 16 + t16) * 32 + kg * 8];
        #pragma unroll
        for (int j = 0; j < 4; ++j)
            bf[j] = *(const frag8*)&Bs[(wn + j * 16 + t16) * 32 + kg * 8];
        #pragma unroll
        for (int i = 0; i < 4; ++i)
            #pragma unroll
            for (int j = 0; j < 4; ++j)
                acc[i][j] = __builtin_amdgcn_mfma_f32_16x16x32_bf16(
                    af[i], bf[j], acc[i][j], 0, 0, 0);
        __syncthreads();
    }

    #pragma unroll
    for (int i = 0; i < 4; ++i)
        #pragma unroll
        for (int j = 0; j < 4; ++j)
            #pragma unroll
            for (int r = 0; r < 4; ++r) {
                int row = bm + wm + i * 16 + quad * 4 + r;
                int col = bn + wn + j * 16 + t16;
                if (CF) ((float*)C)[(size_t)row * N + col] = acc[i][j][r];
                else    ((ushort*)C)[(size_t)row * N + col] = f2bf(acc[i][j][r]);
            }
}

// ---------------------------------------------------------------------------
// RoPE in-place on bf16 [SEQ][strideT]; cos/sin fp32. oscale folds the attn
// 1/sqrt(HD) into Q (fp32, pre-quantization -> exact); 1.0 for K.
// ---------------------------------------------------------------------------
__global__ void rope_kernel(ushort* __restrict__ X, const float* __restrict__ Cos,
                            const float* __restrict__ Sin, int log2nh, int strideT,
                            float oscale)
{
    int idx = blockIdx.x * blockDim.x + threadIdx.x;
    int p = idx & 63;
    int h = (idx >> 6) & ((1 << log2nh) - 1);
    int t = idx >> (6 + log2nh);
    size_t base = (size_t)t * strideT + (size_t)h * 128 + 2 * p;
    ushort2 xv = *(ushort2*)&X[base];
    float x1 = bf2f(xv.x), x2 = bf2f(xv.y);
    float c = Cos[t * 64 + p], s = Sin[t * 64 + p];
    ushort2 ov;
    ov.x = f2bf((x1 * c - x2 * s) * oscale);
    ov.y = f2bf((x1 * s + x2 * c) * oscale);
    *(ushort2*)&X[base] = ov;
}

// ---------------------------------------------------------------------------
// Flash attention, causal, GQA, bf16 internal. Grid (32, NH): block bx
// processes q-tiles {bx, 63-bx} sequentially (constant work / block).
// KVBLK=64. Scores arrive pre-scaled (1/sqrt(HD) folded into Q).
// Row-sum l via extra MFMA against ones (o9).
// T14 async staging: next tile's K/V global loads issue into regs BEFORE
// compute; LDS writes happen after the post-compute barrier (latency hidden).
// Speculative defer-max: mrow inits at 0; fast path needs only the lane-LOCAL
// 4-value max for the trigger test (no cross-lane shfl chain). The full
// shfl-reduce + rescale + exp-recompute runs only when __any lane sees
// lm > mrow+8 (never for this data; preserves correctness for any data).
// ---------------------------------------------------------------------------
__global__ __launch_bounds__(256) void attn_kernel(
    const ushort* __restrict__ Q, const ushort* __restrict__ Kb,
    const ushort* __restrict__ VT, ushort* __restrict__ O)
{
    __shared__ ushort Ks[64][136];      // [t][d], padded
    __shared__ ushort Vt[128][72];      // [d][t], padded
    __shared__ ushort Sp[4][16][72];    // per-wave P tile [q][t]

    const int tid  = threadIdx.x;
    const int lane = tid & 63;
    const int wave = tid >> 6;
    const int quad = lane >> 4;
    const int t16  = lane & 15;
    const int h    = blockIdx.y;
    const int kvh  = h >> 2;

    frag8 vONE;
    #pragma unroll
    for (int i = 0; i < 8; ++i) vONE[i] = (short)0x3F80;   // bf16 1.0

#define LOADREGS(T0)                                                          \
    {                                                                         \
        _Pragma("unroll")                                                     \
        for (int it = 0; it < 4; ++it) {                                      \
            int idx = tid + it * 256;                                         \
            kreg[it] = *(const uint4*)&Kb[(size_t)((T0) + (idx >> 4)) * KVLD  \
                                          + kvh * HD + (idx & 15) * 8];       \
        }                                                                     \
        _Pragma("unroll")                                                     \
        for (int it = 0; it < 4; ++it) {                                      \
            int idx = tid + it * 256;                                         \
            vreg[it] = *(const uint4*)&VT[(size_t)(kvh * HD + (idx >> 3)) * SEQ \
                                          + (T0) + (idx & 7) * 8];            \
        }                                                                     \
    }

#define WRITELDS()                                                            \
    {                                                                         \
        _Pragma("unroll")                                                     \
        for (int it = 0; it < 4; ++it) {                                      \
            int idx = tid + it * 256;                                         \
            *(uint4*)&Ks[idx >> 4][(idx & 15) * 8] = kreg[it];                \
        }                                                                     \
        _Pragma("unroll")                                                     \
        for (int it = 0; it < 4; ++it) {                                      \
            int idx = tid + it * 256;                                         \
            *(uint4*)&Vt[idx >> 3][(idx & 7) * 8] = vreg[it];                 \
        }                                                                     \
    }

    #pragma unroll
    for (int qi = 0; qi < 2; ++qi) {
        const int qt = qi ? (63 - (int)blockIdx.x) : (int)blockIdx.x;
        const int q0 = qt * 64;
        const int qwave = q0 + wave * 16;
        const int qmaxw = qwave + 15;
        const int ntiles = qt + 1;

        frag8 aQ[4];
        #pragma unroll
        for (int kk = 0; kk < 4; ++kk)
            aQ[kk] = *(const frag8*)&Q[(size_t)(qwave + t16) * DIM + h * HD + kk * 32 + quad * 8];

        f32x4 o[8] = {};
        f32x4 o9 = {0.f, 0.f, 0.f, 0.f};   // row-sum accumulator
        float mrow[4] = {0.f, 0.f, 0.f, 0.f};

        uint4 kreg[4], vreg[4];

        // Prologue: stage tile 0.
        LOADREGS(0);
        WRITELDS();
        __syncthreads();

        for (int ti = 0; ti < ntiles; ++ti) {
            const int t0 = ti * 64;

            // Issue next tile's global loads (latency hides under compute).
            if (ti + 1 < ntiles) LOADREGS((ti + 1) * 64);

            const bool hi = (t0 + 32 <= qmaxw);    // wave-uniform upper-half guard

            f32x4 s0 = {0.f, 0.f, 0.f, 0.f};
            f32x4 s1 = {0.f, 0.f, 0.f, 0.f};
            f32x4 s2 = {0.f, 0.f, 0.f, 0.f};
            f32x4 s3 = {0.f, 0.f, 0.f, 0.f};
            #pragma unroll
            for (int kk = 0; kk < 4; ++kk) {
                frag8 b0 = *(const frag8*)&Ks[2 * t16][kk * 32 + quad * 8];
                frag8 b1 = *(const frag8*)&Ks[2 * t16 + 1][kk * 32 + quad * 8];
                s0 = __builtin_amdgcn_mfma_f32_16x16x32_bf16(aQ[kk], b0, s0, 0, 0, 0);
                s1 = __builtin_amdgcn_mfma_f32_16x16x32_bf16(aQ[kk], b1, s1, 0, 0, 0);
            }
            if (hi) {
                #pragma unroll
                for (int kk = 0; kk < 4; ++kk) {
                    frag8 b2 = *(const frag8*)&Ks[32 + 2 * t16][kk * 32 + quad * 8];
                    frag8 b3 = *(const frag8*)&Ks[33 + 2 * t16][kk * 32 + quad * 8];
                    s2 = __builtin_amdgcn_mfma_f32_16x16x32_bf16(aQ[kk], b2, s2, 0, 0, 0);
                    s3 = __builtin_amdgcn_mfma_f32_16x16x32_bf16(aQ[kk], b3, s3, 0, 0, 0);
                }
            }

            const bool mLo = (t0 + 31 > qwave);        // wave-uniform
            const bool mHi = (t0 + 63 > qwave);

            // Fast path: speculative exp with current mrow; lane-local trigger.
            bool trig = false;
            #pragma unroll
            for (int r = 0; r < 4; ++r) {
                int q = qwave + quad * 4 + r;
                float v0 = s0[r];                       // t = t0 + 2*t16
                float v1 = s1[r];                       // t = t0 + 2*t16 + 1
                float v2 = hi ? s2[r] : -30000.f;       // t = t0 + 32 + 2*t16
                float v3 = hi ? s3[r] : -30000.f;       // t = t0 + 33 + 2*t16
                if (mLo) {
                    if (t0 + 2 * t16 > q)      v0 = -30000.f;
                    if (t0 + 2 * t16 + 1 > q)  v1 = -30000.f;
                }
                if (hi && mHi) {
                    if (t0 + 32 + 2 * t16 > q) v2 = -30000.f;
                    if (t0 + 33 + 2 * t16 > q) v3 = -30000.f;
                }
                float lm = fmaxf(fmaxf(v0, v1), fmaxf(v2, v3));
                trig |= (lm > mrow[r] + 8.f);
                float e0 = __expf(v0 - mrow[r]);
                float e1 = __expf(v1 - mrow[r]);
                *(uint*)&Sp[wave][quad * 4 + r][2 * t16] =
                    (uint)f2bf(e0) | ((uint)f2bf(e1) << 16);
                if (hi) {
                    float e2 = __expf(v2 - mrow[r]);
                    float e3 = __expf(v3 - mrow[r]);
                    *(uint*)&Sp[wave][quad * 4 + r][32 + 2 * t16] =
                        (uint)f2bf(e2) | ((uint)f2bf(e3) << 16);
                }
            }

            // Rare fixup: full cross-lane max, rescale, recompute P.
            if (__any(trig)) {
                #pragma unroll
                for (int r = 0; r < 4; ++r) {
                    int q = qwave + quad * 4 + r;
                    float v0 = s0[r], v1 = s1[r];
                    float v2 = hi ? s2[r] : -30000.f;
                    float v3 = hi ? s3[r] : -30000.f;
                    if (mLo) {
                        if (t0 + 2 * t16 > q)      v0 = -30000.f;
                        if (t0 + 2 * t16 + 1 > q)  v1 = -30000.f;
                    }
                    if (hi && mHi) {
                        if (t0 + 32 + 2 * t16 > q) v2 = -30000.f;
                        if (t0 + 33 + 2 * t16 > q) v3 = -30000.f;
                    }
                    float rm = fmaxf(fmaxf(v0, v1), fmaxf(v2, v3));
                    rm = fmaxf(rm, __shfl_xor(rm, 1));
                    rm = fmaxf(rm, __shfl_xor(rm, 2));
                    rm = fmaxf(rm, __shfl_xor(rm, 4));
                    rm = fmaxf(rm, __shfl_xor(rm, 8));
                    float mnew  = fmaxf(mrow[r], rm);
                    float alpha = __expf(mrow[r] - mnew);
                    #pragma unroll
                    for (int j = 0; j < 8; ++j) o[j][r] *= alpha;
                    o9[r] *= alpha;
                    mrow[r] = mnew;
                    float e0 = __expf(v0 - mnew);
                    float e1 = __expf(v1 - mnew);
                    *(uint*)&Sp[wave][quad * 4 + r][2 * t16] =
                        (uint)f2bf(e0) | ((uint)f2bf(e1) << 16);
                    if (hi) {
                        float e2 = __expf(v2 - mnew);
                        float e3 = __expf(v3 - mnew);
                        *(uint*)&Sp[wave][quad * 4 + r][32 + 2 * t16] =
                            (uint)f2bf(e2) | ((uint)f2bf(e3) << 16);
                    }
                }
            }

            frag8 aP0 = *(const frag8*)&Sp[wave][t16][quad * 8];
            #pragma unroll
            for (int j = 0; j < 8; ++j) {
                frag8 bV = *(const frag8*)&Vt[j * 16 + t16][quad * 8];
                o[j] = __builtin_amdgcn_mfma_f32_16x16x32_bf16(aP0, bV, o[j], 0, 0, 0);
            }
            o9 = __builtin_amdgcn_mfma_f32_16x16x32_bf16(aP0, vONE, o9, 0, 0, 0);
            if (hi) {
                frag8 aP1 = *(const frag8*)&Sp[wave][t16][32 + quad * 8];
                #pragma unroll
                for (int j = 0; j < 8; ++j) {
                    frag8 bV = *(const frag8*)&Vt[j * 16 + t16][32 + quad * 8];
                    o[j] = __builtin_amdgcn_mfma_f32_16x16x32_bf16(aP1, bV, o[j], 0, 0, 0);
                }
                o9 = __builtin_amdgcn_mfma_f32_16x16x32_bf16(aP1, vONE, o9, 0, 0, 0);
            }

            __syncthreads();                 // all waves done reading tile ti
            if (ti + 1 < ntiles) {
                WRITELDS();                  // land tile ti+1 (loads long in flight)
                __syncthreads();
            }
        }

        #pragma unroll
        for (int r = 0; r < 4; ++r) {
            float inv = 1.f / fmaxf(o9[r], 1e-20f);
            int row = qwave + quad * 4 + r;
            #pragma unroll
            for (int j = 0; j < 8; ++j)
                O[(size_t)row * DIM + h * HD + j * 16 + t16] = f2bf(o[j][r] * inv);
        }
    }
#undef LOADREGS
#undef WRITELDS
}

// ---------------------------------------------------------------------------
// Memory plan:
//  d_ws (41.94 MB, proven):  Qb[4096][2048] | KVb[4096][1024] | Ab[4096][2048]
//    - pre-attn, Ab hosts WqT[2048][2048] (8.39 MB) + KVT[1024][2048] (8.39 MB)
//    - post-attn, KVb hosts WoT[2048][2048] (8.39 MB, exact fit)
//  d_out (33.55 MB fp32):    Xb bf16 [4096][2048] at offset 0 (16.78 MB)
//                            VT  bf16 [512][4096] at +16.78 MB (4.19 MB)
//    both consumed before the final GEMM overwrites d_out.
// ---------------------------------------------------------------------------
extern "C" void kernel_launch(void* const* d_in, const int* in_sizes, int n_in,
                              void* d_out, int out_size, void* d_ws, size_t ws_size,
                              hipStream_t stream)
{
    const float* x  = (const float*)d_in[0];
    const float* fc = (const float*)d_in[2];
    const float* fs = (const float*)d_in[3];
    const float* wq = (const float*)d_in[5];
    const float* wk = (const float*)d_in[6];
    const float* wv = (const float*)d_in[7];
    const float* wo = (const float*)d_in[8];

    ushort* Qb  = (ushort*)d_ws;
    ushort* KVb = Qb + (size_t)SEQ * DIM;
    ushort* Ab  = KVb + (size_t)SEQ * KVLD;
    ushort* WqT = Ab;                                  // overlay (pre-attn)
    ushort* KVT = Ab + (size_t)DIM * DIM;              // overlay (pre-attn)
    ushort* WoT = KVb;                                 // overlay (post-attn)

    ushort* Xb = (ushort*)d_out;                       // bf16 x in d_out scratch
    ushort* VT = Xb + (size_t)SEQ * DIM;               // bf16 V^T [512][4096]

    dim3 blk(256);

    // Convert inputs to bf16 (x flat; weights transposed).
    cvt_kernel<<<(SEQ * DIM) / 2048, blk, 0, stream>>>(x, Xb);
    convT_kernel<<<dim3(DIM / 32, DIM / 32), blk, 0, stream>>>(wq, WqT, DIM, DIM);
    convT_kernel<<<dim3(512 / 32, DIM / 32), blk, 0, stream>>>(wk, KVT, DIM, 512);
    convT_kernel<<<dim3(512 / 32, DIM / 32), blk, 0, stream>>>(
        wv, KVT + (size_t)512 * DIM, DIM, 512);

    // Projections (bf16 TN, m97-style).
    gemm_tn<0><<<dim3(DIM / 128, SEQ / 128), blk, 0, stream>>>(Xb, WqT, Qb, SEQ, DIM, DIM);
    gemm_tn<0><<<dim3(KVLD / 128, SEQ / 128), blk, 0, stream>>>(Xb, KVT, KVb, SEQ, KVLD, DIM);

    // RoPE on Q (16 heads, stride DIM, attn scale folded in) and K (4 heads).
    rope_kernel<<<(SEQ * NH * 64) / 256, blk, 0, stream>>>(
        Qb, fc, fs, 4, DIM, 0.08838834764831845f);
    rope_kernel<<<(SEQ * NKV * 64) / 256, blk, 0, stream>>>(
        KVb, fc, fs, 2, KVLD, 1.0f);

    // V^T for coalesced attn staging.
    vtrans_kernel<<<dim3(512 / 32, SEQ / 32), blk, 0, stream>>>(KVb, VT);

    // Flash attention -> Ab (weight overlays consumed).
    attn_kernel<<<dim3(32, NH), blk, 0, stream>>>(Qb, KVb, VT, Ab);

    // Output projection (WoT overlays KVb; writes fp32 d_out, consuming Xb/VT).
    convT_kernel<<<dim3(DIM / 32, DIM / 32), blk, 0, stream>>>(wo, WoT, DIM, DIM);
    gemm_tn<1><<<dim3(DIM / 128, SEQ / 128), blk, 0, stream>>>(Ab, WoT, d_out, SEQ, DIM, DIM);
}

// Round 3
// 462.617 us; speedup vs baseline: 1.4357x; 1.4357x over previous
//
#include <hip/hip_runtime.h>
#include <hip/hip_bf16.h>
#include <stdint.h>

#define SEQ 4096
#define DIM 2048
#define NH 16
#define NKV 4
#define HD 128
#define KVLD 1024   /* K|V fused row stride in KVb */

// External I/O is FP32 (proven round 2/6); internal tensors bf16.

using frag8 = __attribute__((ext_vector_type(8))) short;
using f32x4 = __attribute__((ext_vector_type(4))) float;

union VecU { ushort u[8]; uint4 v; };

__device__ __forceinline__ float bf2f(ushort u) {
    union { uint32_t u; float f; } v; v.u = ((uint32_t)u) << 16; return v.f;
}
__device__ __forceinline__ ushort f2bf(float f) {
    union { float f; uint32_t u; } v; v.f = f;
    uint32_t r = v.u + 0x7fffu + ((v.u >> 16) & 1u);
    return (ushort)(r >> 16);
}

__device__ __forceinline__ void glds16(const void* g, void* l) {
    __builtin_amdgcn_global_load_lds(
        (const __attribute__((address_space(1))) void*)g,
        (__attribute__((address_space(3))) void*)l, 16, 0, 0);
}

// ---------------------------------------------------------------------------
// fp32 -> bf16 flat convert (8 elems/thread).
// ---------------------------------------------------------------------------
__global__ __launch_bounds__(256) void cvt_kernel(
    const float* __restrict__ src, ushort* __restrict__ dst)
{
    size_t i = ((size_t)blockIdx.x * 256 + threadIdx.x) * 8;
    float4 f0 = *(const float4*)&src[i];
    float4 f1 = *(const float4*)&src[i + 4];
    VecU t;
    t.u[0] = f2bf(f0.x); t.u[1] = f2bf(f0.y); t.u[2] = f2bf(f0.z); t.u[3] = f2bf(f0.w);
    t.u[4] = f2bf(f1.x); t.u[5] = f2bf(f1.y); t.u[6] = f2bf(f1.z); t.u[7] = f2bf(f1.w);
    *(uint4*)&dst[i] = t.v;
}

// ---------------------------------------------------------------------------
// fp32 [K][N] -> bf16 transposed [N][K], 32x32 tiles.
// ---------------------------------------------------------------------------
__global__ __launch_bounds__(256) void convT_kernel(
    const float* __restrict__ src, ushort* __restrict__ dst, int K, int N)
{
    __shared__ ushort T[32][36];
    int r  = threadIdx.x >> 3;
    int c4 = (threadIdx.x & 7) * 4;
    int bk = blockIdx.y * 32, bn = blockIdx.x * 32;
    float4 v = *(const float4*)&src[(size_t)(bk + r) * N + bn + c4];
    T[r][c4]     = f2bf(v.x); T[r][c4 + 1] = f2bf(v.y);
    T[r][c4 + 2] = f2bf(v.z); T[r][c4 + 3] = f2bf(v.w);
    __syncthreads();
    ushort4 o;
    o.x = T[c4][r]; o.y = T[c4 + 1][r]; o.z = T[c4 + 2][r]; o.w = T[c4 + 3][r];
    *(ushort4*)&dst[(size_t)(bn + r) * K + bk + c4] = o;
}

// ---------------------------------------------------------------------------
// bf16 V transpose: KVb[t][512 + d] (ld KVLD) -> VT[d][t] (ld SEQ), 32x32.
// ---------------------------------------------------------------------------
__global__ __launch_bounds__(256) void vtrans_kernel(
    const ushort* __restrict__ src, ushort* __restrict__ dst)
{
    __shared__ ushort T[32][36];
    int r  = threadIdx.x >> 3;
    int c4 = (threadIdx.x & 7) * 4;
    int bt = blockIdx.y * 32, bd = blockIdx.x * 32;   // t-block, d-block
    ushort4 v = *(const ushort4*)&src[(size_t)(bt + r) * KVLD + 512 + bd + c4];
    T[r][c4] = v.x; T[r][c4 + 1] = v.y; T[r][c4 + 2] = v.z; T[r][c4 + 3] = v.w;
    __syncthreads();
    ushort4 o;
    o.x = T[c4][r]; o.y = T[c4 + 1][r]; o.z = T[c4 + 2][r]; o.w = T[c4 + 3][r];
    *(ushort4*)&dst[(size_t)(bd + r) * SEQ + bt + c4] = o;
}

// ---------------------------------------------------------------------------
// m97-style GEMM: C[M][N] = A[M][K] @ BT[N][K]^T, bf16 in; CF: fp32/bf16 out.
// 128x128 tile, BK=32, global_load_lds(16B).
// ---------------------------------------------------------------------------
template <int CF>
__global__ __launch_bounds__(256) void gemm_tn(
    const ushort* __restrict__ A, const ushort* __restrict__ BT,
    void* __restrict__ C, int M, int N, int K)
{
    __shared__ ushort As[128 * 32];
    __shared__ ushort Bs[128 * 32];

    const int tid  = threadIdx.x;
    const int lane = tid & 63;
    const int wave = tid >> 6;
    const int bm   = blockIdx.y * 128;
    const int bn   = blockIdx.x * 128;
    const int wm   = (wave >> 1) * 64;
    const int wn   = (wave & 1) * 64;
    const int quad = lane >> 4;
    const int t16  = lane & 15;
    const int kg   = quad ^ ((t16 >> 1) & 3);

    f32x4 acc[4][4] = {};

    for (int k0 = 0; k0 < K; k0 += 32) {
        #pragma unroll
        for (int it = 0; it < 2; ++it) {
            int gid = it * 256 + tid;
            int r   = gid >> 2;
            int cs  = (gid & 3) ^ ((gid >> 3) & 3);
            glds16(&A[(size_t)(bm + r) * K + k0 + cs * 8],
                   &As[(it * 256 + wave * 64) * 8]);
            glds16(&BT[(size_t)(bn + r) * K + k0 + cs * 8],
                   &Bs[(it * 256 + wave * 64) * 8]);
        }
        __syncthreads();

        frag8 af[4], bf[4];
        #pragma unroll
        for (int i = 0; i < 4; ++i)
            af[i] = *(const frag8*)&As[(wm + i * 16 + t16) * 32 + kg * 8];
        #pragma unroll
        for (int j = 0; j < 4; ++j)
            bf[j] = *(const frag8*)&Bs[(wn + j * 16 + t16) * 32 + kg * 8];
        #pragma unroll
        for (int i = 0; i < 4; ++i)
            #pragma unroll
            for (int j = 0; j < 4; ++j)
                acc[i][j] = __builtin_amdgcn_mfma_f32_16x16x32_bf16(
                    af[i], bf[j], acc[i][j], 0, 0, 0);
        __syncthreads();
    }

    #pragma unroll
    for (int i = 0; i < 4; ++i)
        #pragma unroll
        for (int j = 0; j < 4; ++j)
            #pragma unroll
            for (int r = 0; r < 4; ++r) {
                int row = bm + wm + i * 16 + quad * 4 + r;
                int col = bn + wn + j * 16 + t16;
                if (CF) ((float*)C)[(size_t)row * N + col] = acc[i][j][r];
                else    ((ushort*)C)[(size_t)row * N + col] = f2bf(acc[i][j][r]);
            }
}

// ---------------------------------------------------------------------------
// Fused QKV projection GEMM: A[SEQ][DIM] @ BT[3072][DIM]^T.
// BT rows 0..2047 = WqT, rows 2048..3071 = KVT (wk|wv) — contiguous at Ab.
// Block-uniform C split (2048 is 128-aligned): cols < 2048 -> Qb (ld DIM),
// cols >= 2048 -> KVb (ld KVLD). Grid 24x32 = 768 blocks (vs 16x32 + 8x32
// separate; KV part was 1 block/CU — fused grid packs 3/CU).
// ---------------------------------------------------------------------------
__global__ __launch_bounds__(256) void gemm_qkv(
    const ushort* __restrict__ A, const ushort* __restrict__ BT,
    ushort* __restrict__ Cq, ushort* __restrict__ Ckv)
{
    const int K = DIM;
    __shared__ ushort As[128 * 32];
    __shared__ ushort Bs[128 * 32];

    const int tid  = threadIdx.x;
    const int lane = tid & 63;
    const int wave = tid >> 6;
    const int bm   = blockIdx.y * 128;
    const int bn   = blockIdx.x * 128;
    const int wm   = (wave >> 1) * 64;
    const int wn   = (wave & 1) * 64;
    const int quad = lane >> 4;
    const int t16  = lane & 15;
    const int kg   = quad ^ ((t16 >> 1) & 3);

    f32x4 acc[4][4] = {};

    for (int k0 = 0; k0 < K; k0 += 32) {
        #pragma unroll
        for (int it = 0; it < 2; ++it) {
            int gid = it * 256 + tid;
            int r   = gid >> 2;
            int cs  = (gid & 3) ^ ((gid >> 3) & 3);
            glds16(&A[(size_t)(bm + r) * K + k0 + cs * 8],
                   &As[(it * 256 + wave * 64) * 8]);
            glds16(&BT[(size_t)(bn + r) * K + k0 + cs * 8],
                   &Bs[(it * 256 + wave * 64) * 8]);
        }
        __syncthreads();

        frag8 af[4], bf[4];
        #pragma unroll
        for (int i = 0; i < 4; ++i)
            af[i] = *(const frag8*)&As[(wm + i * 16 + t16) * 32 + kg * 8];
        #pragma unroll
        for (int j = 0; j < 4; ++j)
            bf[j] = *(const frag8*)&Bs[(wn + j * 16 + t16) * 32 + kg * 8];
        #pragma unroll
        for (int i = 0; i < 4; ++i)
            #pragma unroll
            for (int j = 0; j < 4; ++j)
                acc[i][j] = __builtin_amdgcn_mfma_f32_16x16x32_bf16(
                    af[i], bf[j], acc[i][j], 0, 0, 0);
        __syncthreads();
    }

    // Block-uniform output select.
    ushort* C;
    int ldc, cb;
    if (bn < 2048) { C = Cq;  ldc = DIM;  cb = 0; }
    else           { C = Ckv; ldc = KVLD; cb = 2048; }

    #pragma unroll
    for (int i = 0; i < 4; ++i)
        #pragma unroll
        for (int j = 0; j < 4; ++j)
            #pragma unroll
            for (int r = 0; r < 4; ++r) {
                int row = bm + wm + i * 16 + quad * 4 + r;
                int col = bn + wn + j * 16 + t16;
                C[(size_t)row * ldc + (col - cb)] = f2bf(acc[i][j][r]);
            }
}

// ---------------------------------------------------------------------------
// RoPE in-place on bf16 [SEQ][strideT]; cos/sin fp32. oscale folds the attn
// 1/sqrt(HD) into Q (fp32, pre-quantization -> exact); 1.0 for K.
// ---------------------------------------------------------------------------
__global__ void rope_kernel(ushort* __restrict__ X, const float* __restrict__ Cos,
                            const float* __restrict__ Sin, int log2nh, int strideT,
                            float oscale)
{
    int idx = blockIdx.x * blockDim.x + threadIdx.x;
    int p = idx & 63;
    int h = (idx >> 6) & ((1 << log2nh) - 1);
    int t = idx >> (6 + log2nh);
    size_t base = (size_t)t * strideT + (size_t)h * 128 + 2 * p;
    ushort2 xv = *(ushort2*)&X[base];
    float x1 = bf2f(xv.x), x2 = bf2f(xv.y);
    float c = Cos[t * 64 + p], s = Sin[t * 64 + p];
    ushort2 ov;
    ov.x = f2bf((x1 * c - x2 * s) * oscale);
    ov.y = f2bf((x1 * s + x2 * c) * oscale);
    *(ushort2*)&X[base] = ov;
}

// ---------------------------------------------------------------------------
// Flash attention, causal, GQA, bf16 internal. Grid (32, NH): block bx
// processes q-tiles {bx, 63-bx} sequentially (constant work / block).
// KVBLK=64. Scores arrive pre-scaled (1/sqrt(HD) folded into Q by rope).
// Row-sum l via extra MFMA against ones (o9). Defer-max (T13, THR=8).
// [Round-1 version, verbatim: 187 µs measured. Round-2's reg-staged T14
//  spilled to scratch (WRITE_SIZE 16->662 MB) and regressed 2x — reverted.]
// ---------------------------------------------------------------------------
__global__ __launch_bounds__(256) void attn_kernel(
    const ushort* __restrict__ Q, const ushort* __restrict__ Kb,
    const ushort* __restrict__ VT, ushort* __restrict__ O)
{
    __shared__ ushort Ks[64][136];      // [t][d], padded
    __shared__ ushort Vt[128][72];      // [d][t], padded
    __shared__ ushort Sp[4][16][72];    // per-wave P tile [q][t]

    const int tid  = threadIdx.x;
    const int lane = tid & 63;
    const int wave = tid >> 6;
    const int quad = lane >> 4;
    const int t16  = lane & 15;
    const int h    = blockIdx.y;
    const int kvh  = h >> 2;

    frag8 vONE;
    #pragma unroll
    for (int i = 0; i < 8; ++i) vONE[i] = (short)0x3F80;   // bf16 1.0

    #pragma unroll
    for (int qi = 0; qi < 2; ++qi) {
        const int qt = qi ? (63 - (int)blockIdx.x) : (int)blockIdx.x;
        const int q0 = qt * 64;
        const int qwave = q0 + wave * 16;
        const int qmaxw = qwave + 15;

        frag8 aQ[4];
        #pragma unroll
        for (int kk = 0; kk < 4; ++kk)
            aQ[kk] = *(const frag8*)&Q[(size_t)(qwave + t16) * DIM + h * HD + kk * 32 + quad * 8];

        f32x4 o[8] = {};
        f32x4 o9 = {0.f, 0.f, 0.f, 0.f};   // row-sum accumulator (all cols equal)
        float mrow[4];
        #pragma unroll
        for (int r = 0; r < 4; ++r) mrow[r] = -30000.f;

        for (int t0 = 0; t0 <= q0 + 63; t0 += 64) {
            // Stage K tile: 64 rows x 128 d (uint4 from fused KVb).
            #pragma unroll
            for (int it = 0; it < 4; ++it) {
                int idx = tid + it * 256;
                int tt  = idx >> 4;
                int c   = (idx & 15) * 8;
                *(uint4*)&Ks[tt][c] =
                    *(const uint4*)&Kb[(size_t)(t0 + tt) * KVLD + kvh * HD + c];
            }
            // Stage V^T tile: 128 d x 64 t (uint4 from pre-transposed VT).
            #pragma unroll
            for (int it = 0; it < 4; ++it) {
                int idx = tid + it * 256;
                int d   = idx >> 3;                // 0..127
                int tq  = (idx & 7) * 8;           // 0..56
                *(uint4*)&Vt[d][tq] =
                    *(const uint4*)&VT[(size_t)(kvh * HD + d) * SEQ + t0 + tq];
            }
            __syncthreads();

            const bool hi = (t0 + 32 <= qmaxw);    // wave-uniform upper-half guard
            {
                f32x4 s0 = {0.f, 0.f, 0.f, 0.f};
                f32x4 s1 = {0.f, 0.f, 0.f, 0.f};
                f32x4 s2 = {0.f, 0.f, 0.f, 0.f};
                f32x4 s3 = {0.f, 0.f, 0.f, 0.f};
                #pragma unroll
                for (int kk = 0; kk < 4; ++kk) {
                    frag8 b0 = *(const frag8*)&Ks[2 * t16][kk * 32 + quad * 8];
                    frag8 b1 = *(const frag8*)&Ks[2 * t16 + 1][kk * 32 + quad * 8];
                    s0 = __builtin_amdgcn_mfma_f32_16x16x32_bf16(aQ[kk], b0, s0, 0, 0, 0);
                    s1 = __builtin_amdgcn_mfma_f32_16x16x32_bf16(aQ[kk], b1, s1, 0, 0, 0);
                }
                if (hi) {
                    #pragma unroll
                    for (int kk = 0; kk < 4; ++kk) {
                        frag8 b2 = *(const frag8*)&Ks[32 + 2 * t16][kk * 32 + quad * 8];
                        frag8 b3 = *(const frag8*)&Ks[33 + 2 * t16][kk * 32 + quad * 8];
                        s2 = __builtin_amdgcn_mfma_f32_16x16x32_bf16(aQ[kk], b2, s2, 0, 0, 0);
                        s3 = __builtin_amdgcn_mfma_f32_16x16x32_bf16(aQ[kk], b3, s3, 0, 0, 0);
                    }
                }

                const bool mLo = (t0 + 31 > qwave);        // wave-uniform
                const bool mHi = (t0 + 63 > qwave);
                float v[4][4];
                float mnew[4];
                bool trig = false;
                #pragma unroll
                for (int r = 0; r < 4; ++r) {
                    int q = qwave + quad * 4 + r;
                    float v0 = s0[r];                       // t = t0 + 2*t16
                    float v1 = s1[r];                       // t = t0 + 2*t16 + 1
                    float v2 = hi ? s2[r] : -30000.f;       // t = t0 + 32 + 2*t16
                    float v3 = hi ? s3[r] : -30000.f;       // t = t0 + 33 + 2*t16
                    if (mLo) {
                        if (t0 + 2 * t16 > q)      v0 = -30000.f;
                        if (t0 + 2 * t16 + 1 > q)  v1 = -30000.f;
                    }
                    if (hi && mHi) {
                        if (t0 + 32 + 2 * t16 > q) v2 = -30000.f;
                        if (t0 + 33 + 2 * t16 > q) v3 = -30000.f;
                    }
                    float rm = fmaxf(fmaxf(v0, v1), fmaxf(v2, v3));
                    rm = fmaxf(rm, __shfl_xor(rm, 1));
                    rm = fmaxf(rm, __shfl_xor(rm, 2));
                    rm = fmaxf(rm, __shfl_xor(rm, 4));
                    rm = fmaxf(rm, __shfl_xor(rm, 8));
                    mnew[r] = fmaxf(mrow[r], rm);
                    trig |= (rm > mrow[r] + 8.f);
                    v[r][0] = v0; v[r][1] = v1; v[r][2] = v2; v[r][3] = v3;
                }
                if (__any(trig)) {                          // rare after tile 0
                    #pragma unroll
                    for (int r = 0; r < 4; ++r) {
                        float alpha = __expf(mrow[r] - mnew[r]);
                        mrow[r] = mnew[r];
                        #pragma unroll
                        for (int j = 0; j < 8; ++j) o[j][r] *= alpha;
                        o9[r] *= alpha;
                    }
                }
                #pragma unroll
                for (int r = 0; r < 4; ++r) {
                    float e0 = __expf(v[r][0] - mrow[r]);
                    float e1 = __expf(v[r][1] - mrow[r]);
                    uint pv = (uint)f2bf(e0) | ((uint)f2bf(e1) << 16);
                    *(uint*)&Sp[wave][quad * 4 + r][2 * t16] = pv;
                    if (hi) {
                        float e2 = __expf(v[r][2] - mrow[r]);
                        float e3 = __expf(v[r][3] - mrow[r]);
                        uint ph = (uint)f2bf(e2) | ((uint)f2bf(e3) << 16);
                        *(uint*)&Sp[wave][quad * 4 + r][32 + 2 * t16] = ph;
                    }
                }

                frag8 aP0 = *(const frag8*)&Sp[wave][t16][quad * 8];
                #pragma unroll
                for (int j = 0; j < 8; ++j) {
                    frag8 bV = *(const frag8*)&Vt[j * 16 + t16][quad * 8];
                    o[j] = __builtin_amdgcn_mfma_f32_16x16x32_bf16(aP0, bV, o[j], 0, 0, 0);
                }
                o9 = __builtin_amdgcn_mfma_f32_16x16x32_bf16(aP0, vONE, o9, 0, 0, 0);
                if (hi) {
                    frag8 aP1 = *(const frag8*)&Sp[wave][t16][32 + quad * 8];
                    #pragma unroll
                    for (int j = 0; j < 8; ++j) {
                        frag8 bV = *(const frag8*)&Vt[j * 16 + t16][32 + quad * 8];
                        o[j] = __builtin_amdgcn_mfma_f32_16x16x32_bf16(aP1, bV, o[j], 0, 0, 0);
                    }
                    o9 = __builtin_amdgcn_mfma_f32_16x16x32_bf16(aP1, vONE, o9, 0, 0, 0);
                }
            }
            __syncthreads();
        }

        #pragma unroll
        for (int r = 0; r < 4; ++r) {
            float inv = 1.f / fmaxf(o9[r], 1e-20f);
            int row = qwave + quad * 4 + r;
            #pragma unroll
            for (int j = 0; j < 8; ++j)
                O[(size_t)row * DIM + h * HD + j * 16 + t16] = f2bf(o[j][r] * inv);
        }
    }
}

// ---------------------------------------------------------------------------
// Memory plan:
//  d_ws (41.94 MB, proven):  Qb[4096][2048] | KVb[4096][1024] | Ab[4096][2048]
//    - pre-attn, Ab hosts WqT[2048][2048] + KVT[1024][2048] = contiguous
//      BT[3072][2048] for the fused QKV GEMM
//    - post-attn, KVb hosts WoT[2048][2048] (8.39 MB, exact fit)
//  d_out (33.55 MB fp32):    Xb bf16 [4096][2048] at offset 0 (16.78 MB)
//                            VT  bf16 [512][4096] at +16.78 MB (4.19 MB)
//    both consumed before the final GEMM overwrites d_out.
// ---------------------------------------------------------------------------
extern "C" void kernel_launch(void* const* d_in, const int* in_sizes, int n_in,
                              void* d_out, int out_size, void* d_ws, size_t ws_size,
                              hipStream_t stream)
{
    const float* x  = (const float*)d_in[0];
    const float* fc = (const float*)d_in[2];
    const float* fs = (const float*)d_in[3];
    const float* wq = (const float*)d_in[5];
    const float* wk = (const float*)d_in[6];
    const float* wv = (const float*)d_in[7];
    const float* wo = (const float*)d_in[8];

    ushort* Qb  = (ushort*)d_ws;
    ushort* KVb = Qb + (size_t)SEQ * DIM;
    ushort* Ab  = KVb + (size_t)SEQ * KVLD;
    ushort* WqT = Ab;                                  // overlay (pre-attn)
    ushort* KVT = Ab + (size_t)DIM * DIM;              // overlay (pre-attn)
    ushort* WoT = KVb;                                 // overlay (post-attn)

    ushort* Xb = (ushort*)d_out;                       // bf16 x in d_out scratch
    ushort* VT = Xb + (size_t)SEQ * DIM;               // bf16 V^T [512][4096]

    dim3 blk(256);

    // Convert inputs to bf16 (x flat; weights transposed).
    cvt_kernel<<<(SEQ * DIM) / 2048, blk, 0, stream>>>(x, Xb);
    convT_kernel<<<dim3(DIM / 32, DIM / 32), blk, 0, stream>>>(wq, WqT, DIM, DIM);
    convT_kernel<<<dim3(512 / 32, DIM / 32), blk, 0, stream>>>(wk, KVT, DIM, 512);
    convT_kernel<<<dim3(512 / 32, DIM / 32), blk, 0, stream>>>(
        wv, KVT + (size_t)512 * DIM, DIM, 512);

    // Fused QKV projection (BT = WqT|KVT contiguous at Ab, N=3072).
    gemm_qkv<<<dim3(3072 / 128, SEQ / 128), blk, 0, stream>>>(Xb, Ab, Qb, KVb);

    // RoPE on Q (16 heads, stride DIM, attn scale folded in) and K (4 heads).
    rope_kernel<<<(SEQ * NH * 64) / 256, blk, 0, stream>>>(
        Qb, fc, fs, 4, DIM, 0.08838834764831845f);
    rope_kernel<<<(SEQ * NKV * 64) / 256, blk, 0, stream>>>(
        KVb, fc, fs, 2, KVLD, 1.0f);

    // V^T for coalesced attn staging.
    vtrans_kernel<<<dim3(512 / 32, SEQ / 32), blk, 0, stream>>>(KVb, VT);

    // Flash attention -> Ab (weight overlays consumed).
    attn_kernel<<<dim3(32, NH), blk, 0, stream>>>(Qb, KVb, VT, Ab);

    // Output projection (WoT overlays KVb; writes fp32 d_out, consuming Xb/VT).
    convT_kernel<<<dim3(DIM / 32, DIM / 32), blk, 0, stream>>>(wo, WoT, DIM, DIM);
    gemm_tn<1><<<dim3(DIM / 128, SEQ / 128), blk, 0, stream>>>(Ab, WoT, d_out, SEQ, DIM, DIM);
}

// Round 4
// 452.793 us; speedup vs baseline: 1.4669x; 1.0217x over previous
//
#include <hip/hip_runtime.h>
#include <hip/hip_bf16.h>
#include <stdint.h>

#define SEQ 4096
#define DIM 2048
#define NH 16
#define NKV 4
#define HD 128
#define KVLD 1024   /* K|V fused row stride in KVb */

// External I/O is FP32 (proven round 2/6); internal tensors bf16.

using frag8 = __attribute__((ext_vector_type(8))) short;
using f32x4 = __attribute__((ext_vector_type(4))) float;

union VecU { ushort u[8]; uint4 v; };

__device__ __forceinline__ float bf2f(ushort u) {
    union { uint32_t u; float f; } v; v.u = ((uint32_t)u) << 16; return v.f;
}
__device__ __forceinline__ ushort f2bf(float f) {
    union { float f; uint32_t u; } v; v.f = f;
    uint32_t r = v.u + 0x7fffu + ((v.u >> 16) & 1u);
    return (ushort)(r >> 16);
}

__device__ __forceinline__ void glds16(const void* g, void* l) {
    __builtin_amdgcn_global_load_lds(
        (const __attribute__((address_space(1))) void*)g,
        (__attribute__((address_space(3))) void*)l, 16, 0, 0);
}

// ---------------------------------------------------------------------------
// fp32 -> bf16 flat convert (8 elems/thread).
// ---------------------------------------------------------------------------
__global__ __launch_bounds__(256) void cvt_kernel(
    const float* __restrict__ src, ushort* __restrict__ dst)
{
    size_t i = ((size_t)blockIdx.x * 256 + threadIdx.x) * 8;
    float4 f0 = *(const float4*)&src[i];
    float4 f1 = *(const float4*)&src[i + 4];
    VecU t;
    t.u[0] = f2bf(f0.x); t.u[1] = f2bf(f0.y); t.u[2] = f2bf(f0.z); t.u[3] = f2bf(f0.w);
    t.u[4] = f2bf(f1.x); t.u[5] = f2bf(f1.y); t.u[6] = f2bf(f1.z); t.u[7] = f2bf(f1.w);
    *(uint4*)&dst[i] = t.v;
}

// ---------------------------------------------------------------------------
// fp32 [K][N] -> bf16 transposed [N][K], 32x32 tiles.
// ---------------------------------------------------------------------------
__global__ __launch_bounds__(256) void convT_kernel(
    const float* __restrict__ src, ushort* __restrict__ dst, int K, int N)
{
    __shared__ ushort T[32][36];
    int r  = threadIdx.x >> 3;
    int c4 = (threadIdx.x & 7) * 4;
    int bk = blockIdx.y * 32, bn = blockIdx.x * 32;
    float4 v = *(const float4*)&src[(size_t)(bk + r) * N + bn + c4];
    T[r][c4]     = f2bf(v.x); T[r][c4 + 1] = f2bf(v.y);
    T[r][c4 + 2] = f2bf(v.z); T[r][c4 + 3] = f2bf(v.w);
    __syncthreads();
    ushort4 o;
    o.x = T[c4][r]; o.y = T[c4 + 1][r]; o.z = T[c4 + 2][r]; o.w = T[c4 + 3][r];
    *(ushort4*)&dst[(size_t)(bn + r) * K + bk + c4] = o;
}

// ---------------------------------------------------------------------------
// bf16 V transpose: KVb[t][512 + d] (ld KVLD) -> VT[d][t] (ld SEQ), 32x32.
// ---------------------------------------------------------------------------
__global__ __launch_bounds__(256) void vtrans_kernel(
    const ushort* __restrict__ src, ushort* __restrict__ dst)
{
    __shared__ ushort T[32][36];
    int r  = threadIdx.x >> 3;
    int c4 = (threadIdx.x & 7) * 4;
    int bt = blockIdx.y * 32, bd = blockIdx.x * 32;   // t-block, d-block
    ushort4 v = *(const ushort4*)&src[(size_t)(bt + r) * KVLD + 512 + bd + c4];
    T[r][c4] = v.x; T[r][c4 + 1] = v.y; T[r][c4 + 2] = v.z; T[r][c4 + 3] = v.w;
    __syncthreads();
    ushort4 o;
    o.x = T[c4][r]; o.y = T[c4 + 1][r]; o.z = T[c4 + 2][r]; o.w = T[c4 + 3][r];
    *(ushort4*)&dst[(size_t)(bd + r) * SEQ + bt + c4] = o;
}

// ---------------------------------------------------------------------------
// m97-style GEMM: C[M][N] = A[M][K] @ BT[N][K]^T, bf16 in; CF: fp32/bf16 out.
// 128x128 tile, BK=32, global_load_lds(16B).
// ---------------------------------------------------------------------------
template <int CF>
__global__ __launch_bounds__(256) void gemm_tn(
    const ushort* __restrict__ A, const ushort* __restrict__ BT,
    void* __restrict__ C, int M, int N, int K)
{
    __shared__ ushort As[128 * 32];
    __shared__ ushort Bs[128 * 32];

    const int tid  = threadIdx.x;
    const int lane = tid & 63;
    const int wave = tid >> 6;
    const int bm   = blockIdx.y * 128;
    const int bn   = blockIdx.x * 128;
    const int wm   = (wave >> 1) * 64;
    const int wn   = (wave & 1) * 64;
    const int quad = lane >> 4;
    const int t16  = lane & 15;
    const int kg   = quad ^ ((t16 >> 1) & 3);

    f32x4 acc[4][4] = {};

    for (int k0 = 0; k0 < K; k0 += 32) {
        #pragma unroll
        for (int it = 0; it < 2; ++it) {
            int gid = it * 256 + tid;
            int r   = gid >> 2;
            int cs  = (gid & 3) ^ ((gid >> 3) & 3);
            glds16(&A[(size_t)(bm + r) * K + k0 + cs * 8],
                   &As[(it * 256 + wave * 64) * 8]);
            glds16(&BT[(size_t)(bn + r) * K + k0 + cs * 8],
                   &Bs[(it * 256 + wave * 64) * 8]);
        }
        __syncthreads();

        frag8 af[4], bf[4];
        #pragma unroll
        for (int i = 0; i < 4; ++i)
            af[i] = *(const frag8*)&As[(wm + i * 16 + t16) * 32 + kg * 8];
        #pragma unroll
        for (int j = 0; j < 4; ++j)
            bf[j] = *(const frag8*)&Bs[(wn + j * 16 + t16) * 32 + kg * 8];
        #pragma unroll
        for (int i = 0; i < 4; ++i)
            #pragma unroll
            for (int j = 0; j < 4; ++j)
                acc[i][j] = __builtin_amdgcn_mfma_f32_16x16x32_bf16(
                    af[i], bf[j], acc[i][j], 0, 0, 0);
        __syncthreads();
    }

    #pragma unroll
    for (int i = 0; i < 4; ++i)
        #pragma unroll
        for (int j = 0; j < 4; ++j)
            #pragma unroll
            for (int r = 0; r < 4; ++r) {
                int row = bm + wm + i * 16 + quad * 4 + r;
                int col = bn + wn + j * 16 + t16;
                if (CF) ((float*)C)[(size_t)row * N + col] = acc[i][j][r];
                else    ((ushort*)C)[(size_t)row * N + col] = f2bf(acc[i][j][r]);
            }
}

// ---------------------------------------------------------------------------
// Fused QKV projection GEMM: A[SEQ][DIM] @ BT[3072][DIM]^T.
// BT rows 0..2047 = WqT, rows 2048..3071 = KVT (wk|wv) — contiguous at Ab.
// Block-uniform C split (2048 is 128-aligned): cols < 2048 -> Qb (ld DIM),
// cols >= 2048 -> KVb (ld KVLD). Grid 24x32 = 768 blocks.
// ---------------------------------------------------------------------------
__global__ __launch_bounds__(256) void gemm_qkv(
    const ushort* __restrict__ A, const ushort* __restrict__ BT,
    ushort* __restrict__ Cq, ushort* __restrict__ Ckv)
{
    const int K = DIM;
    __shared__ ushort As[128 * 32];
    __shared__ ushort Bs[128 * 32];

    const int tid  = threadIdx.x;
    const int lane = tid & 63;
    const int wave = tid >> 6;
    const int bm   = blockIdx.y * 128;
    const int bn   = blockIdx.x * 128;
    const int wm   = (wave >> 1) * 64;
    const int wn   = (wave & 1) * 64;
    const int quad = lane >> 4;
    const int t16  = lane & 15;
    const int kg   = quad ^ ((t16 >> 1) & 3);

    f32x4 acc[4][4] = {};

    for (int k0 = 0; k0 < K; k0 += 32) {
        #pragma unroll
        for (int it = 0; it < 2; ++it) {
            int gid = it * 256 + tid;
            int r   = gid >> 2;
            int cs  = (gid & 3) ^ ((gid >> 3) & 3);
            glds16(&A[(size_t)(bm + r) * K + k0 + cs * 8],
                   &As[(it * 256 + wave * 64) * 8]);
            glds16(&BT[(size_t)(bn + r) * K + k0 + cs * 8],
                   &Bs[(it * 256 + wave * 64) * 8]);
        }
        __syncthreads();

        frag8 af[4], bf[4];
        #pragma unroll
        for (int i = 0; i < 4; ++i)
            af[i] = *(const frag8*)&As[(wm + i * 16 + t16) * 32 + kg * 8];
        #pragma unroll
        for (int j = 0; j < 4; ++j)
            bf[j] = *(const frag8*)&Bs[(wn + j * 16 + t16) * 32 + kg * 8];
        #pragma unroll
        for (int i = 0; i < 4; ++i)
            #pragma unroll
            for (int j = 0; j < 4; ++j)
                acc[i][j] = __builtin_amdgcn_mfma_f32_16x16x32_bf16(
                    af[i], bf[j], acc[i][j], 0, 0, 0);
        __syncthreads();
    }

    // Block-uniform output select.
    ushort* C;
    int ldc, cb;
    if (bn < 2048) { C = Cq;  ldc = DIM;  cb = 0; }
    else           { C = Ckv; ldc = KVLD; cb = 2048; }

    #pragma unroll
    for (int i = 0; i < 4; ++i)
        #pragma unroll
        for (int j = 0; j < 4; ++j)
            #pragma unroll
            for (int r = 0; r < 4; ++r) {
                int row = bm + wm + i * 16 + quad * 4 + r;
                int col = bn + wn + j * 16 + t16;
                C[(size_t)row * ldc + (col - cb)] = f2bf(acc[i][j][r]);
            }
}

// ---------------------------------------------------------------------------
// RoPE in-place on bf16 [SEQ][strideT]; cos/sin fp32. oscale folds the attn
// 1/sqrt(HD) into Q (fp32, pre-quantization -> exact); 1.0 for K.
// ---------------------------------------------------------------------------
__global__ void rope_kernel(ushort* __restrict__ X, const float* __restrict__ Cos,
                            const float* __restrict__ Sin, int log2nh, int strideT,
                            float oscale)
{
    int idx = blockIdx.x * blockDim.x + threadIdx.x;
    int p = idx & 63;
    int h = (idx >> 6) & ((1 << log2nh) - 1);
    int t = idx >> (6 + log2nh);
    size_t base = (size_t)t * strideT + (size_t)h * 128 + 2 * p;
    ushort2 xv = *(ushort2*)&X[base];
    float x1 = bf2f(xv.x), x2 = bf2f(xv.y);
    float c = Cos[t * 64 + p], s = Sin[t * 64 + p];
    ushort2 ov;
    ov.x = f2bf((x1 * c - x2 * s) * oscale);
    ov.y = f2bf((x1 * s + x2 * c) * oscale);
    *(ushort2*)&X[base] = ov;
}

// ---------------------------------------------------------------------------
// Flash attention, causal, GQA, bf16 internal. Grid (NH, 64): one q-tile per
// block; h = blockIdx.x (fast dim), qt = 63 - blockIdx.y so dispatch order is
// globally descending in work (all heads' qt=63 first -> no straggler tail;
// max block = 64 tile-units vs mean CU load 130). 1024 blocks, 3/CU resident
// (45 KB LDS) = 12 waves/CU: inter-block overlap hides staging latency that
// the 2-block/CU pairing exposed. T5 setprio(1) around MFMA clusters (m191).
// KVBLK=64; scores pre-scaled (1/sqrt(HD) in Q); row-sum via ones-MFMA (o9);
// defer-max (T13, THR=8).
// ---------------------------------------------------------------------------
__global__ __launch_bounds__(256) void attn_kernel(
    const ushort* __restrict__ Q, const ushort* __restrict__ Kb,
    const ushort* __restrict__ VT, ushort* __restrict__ O)
{
    __shared__ ushort Ks[64][136];      // [t][d], padded
    __shared__ ushort Vt[128][72];      // [d][t], padded
    __shared__ ushort Sp[4][16][72];    // per-wave P tile [q][t]

    const int tid  = threadIdx.x;
    const int lane = tid & 63;
    const int wave = tid >> 6;
    const int quad = lane >> 4;
    const int t16  = lane & 15;
    const int h    = blockIdx.x;
    const int kvh  = h >> 2;

    frag8 vONE;
    #pragma unroll
    for (int i = 0; i < 8; ++i) vONE[i] = (short)0x3F80;   // bf16 1.0

    const int qt = 63 - (int)blockIdx.y;
    const int q0 = qt * 64;
    const int qwave = q0 + wave * 16;
    const int qmaxw = qwave + 15;

    frag8 aQ[4];
    #pragma unroll
    for (int kk = 0; kk < 4; ++kk)
        aQ[kk] = *(const frag8*)&Q[(size_t)(qwave + t16) * DIM + h * HD + kk * 32 + quad * 8];

    f32x4 o[8] = {};
    f32x4 o9 = {0.f, 0.f, 0.f, 0.f};   // row-sum accumulator (all cols equal)
    float mrow[4];
    #pragma unroll
    for (int r = 0; r < 4; ++r) mrow[r] = -30000.f;

    for (int t0 = 0; t0 <= q0 + 63; t0 += 64) {
        // Stage K tile: 64 rows x 128 d (uint4 from fused KVb).
        #pragma unroll
        for (int it = 0; it < 4; ++it) {
            int idx = tid + it * 256;
            int tt  = idx >> 4;
            int c   = (idx & 15) * 8;
            *(uint4*)&Ks[tt][c] =
                *(const uint4*)&Kb[(size_t)(t0 + tt) * KVLD + kvh * HD + c];
        }
        // Stage V^T tile: 128 d x 64 t (uint4 from pre-transposed VT).
        #pragma unroll
        for (int it = 0; it < 4; ++it) {
            int idx = tid + it * 256;
            int d   = idx >> 3;                // 0..127
            int tq  = (idx & 7) * 8;           // 0..56
            *(uint4*)&Vt[d][tq] =
                *(const uint4*)&VT[(size_t)(kvh * HD + d) * SEQ + t0 + tq];
        }
        __syncthreads();

        const bool hi = (t0 + 32 <= qmaxw);    // wave-uniform upper-half guard
        {
            f32x4 s0 = {0.f, 0.f, 0.f, 0.f};
            f32x4 s1 = {0.f, 0.f, 0.f, 0.f};
            f32x4 s2 = {0.f, 0.f, 0.f, 0.f};
            f32x4 s3 = {0.f, 0.f, 0.f, 0.f};
            __builtin_amdgcn_s_setprio(1);
            #pragma unroll
            for (int kk = 0; kk < 4; ++kk) {
                frag8 b0 = *(const frag8*)&Ks[2 * t16][kk * 32 + quad * 8];
                frag8 b1 = *(const frag8*)&Ks[2 * t16 + 1][kk * 32 + quad * 8];
                s0 = __builtin_amdgcn_mfma_f32_16x16x32_bf16(aQ[kk], b0, s0, 0, 0, 0);
                s1 = __builtin_amdgcn_mfma_f32_16x16x32_bf16(aQ[kk], b1, s1, 0, 0, 0);
            }
            if (hi) {
                #pragma unroll
                for (int kk = 0; kk < 4; ++kk) {
                    frag8 b2 = *(const frag8*)&Ks[32 + 2 * t16][kk * 32 + quad * 8];
                    frag8 b3 = *(const frag8*)&Ks[33 + 2 * t16][kk * 32 + quad * 8];
                    s2 = __builtin_amdgcn_mfma_f32_16x16x32_bf16(aQ[kk], b2, s2, 0, 0, 0);
                    s3 = __builtin_amdgcn_mfma_f32_16x16x32_bf16(aQ[kk], b3, s3, 0, 0, 0);
                }
            }
            __builtin_amdgcn_s_setprio(0);

            const bool mLo = (t0 + 31 > qwave);        // wave-uniform
            const bool mHi = (t0 + 63 > qwave);
            float v[4][4];
            float mnew[4];
            bool trig = false;
            #pragma unroll
            for (int r = 0; r < 4; ++r) {
                int q = qwave + quad * 4 + r;
                float v0 = s0[r];                       // t = t0 + 2*t16
                float v1 = s1[r];                       // t = t0 + 2*t16 + 1
                float v2 = hi ? s2[r] : -30000.f;       // t = t0 + 32 + 2*t16
                float v3 = hi ? s3[r] : -30000.f;       // t = t0 + 33 + 2*t16
                if (mLo) {
                    if (t0 + 2 * t16 > q)      v0 = -30000.f;
                    if (t0 + 2 * t16 + 1 > q)  v1 = -30000.f;
                }
                if (hi && mHi) {
                    if (t0 + 32 + 2 * t16 > q) v2 = -30000.f;
                    if (t0 + 33 + 2 * t16 > q) v3 = -30000.f;
                }
                float rm = fmaxf(fmaxf(v0, v1), fmaxf(v2, v3));
                rm = fmaxf(rm, __shfl_xor(rm, 1));
                rm = fmaxf(rm, __shfl_xor(rm, 2));
                rm = fmaxf(rm, __shfl_xor(rm, 4));
                rm = fmaxf(rm, __shfl_xor(rm, 8));
                mnew[r] = fmaxf(mrow[r], rm);
                trig |= (rm > mrow[r] + 8.f);
                v[r][0] = v0; v[r][1] = v1; v[r][2] = v2; v[r][3] = v3;
            }
            if (__any(trig)) {                          // rare after tile 0
                #pragma unroll
                for (int r = 0; r < 4; ++r) {
                    float alpha = __expf(mrow[r] - mnew[r]);
                    mrow[r] = mnew[r];
                    #pragma unroll
                    for (int j = 0; j < 8; ++j) o[j][r] *= alpha;
                    o9[r] *= alpha;
                }
            }
            #pragma unroll
            for (int r = 0; r < 4; ++r) {
                float e0 = __expf(v[r][0] - mrow[r]);
                float e1 = __expf(v[r][1] - mrow[r]);
                uint pv = (uint)f2bf(e0) | ((uint)f2bf(e1) << 16);
                *(uint*)&Sp[wave][quad * 4 + r][2 * t16] = pv;
                if (hi) {
                    float e2 = __expf(v[r][2] - mrow[r]);
                    float e3 = __expf(v[r][3] - mrow[r]);
                    uint ph = (uint)f2bf(e2) | ((uint)f2bf(e3) << 16);
                    *(uint*)&Sp[wave][quad * 4 + r][32 + 2 * t16] = ph;
                }
            }

            frag8 aP0 = *(const frag8*)&Sp[wave][t16][quad * 8];
            __builtin_amdgcn_s_setprio(1);
            #pragma unroll
            for (int j = 0; j < 8; ++j) {
                frag8 bV = *(const frag8*)&Vt[j * 16 + t16][quad * 8];
                o[j] = __builtin_amdgcn_mfma_f32_16x16x32_bf16(aP0, bV, o[j], 0, 0, 0);
            }
            o9 = __builtin_amdgcn_mfma_f32_16x16x32_bf16(aP0, vONE, o9, 0, 0, 0);
            if (hi) {
                frag8 aP1 = *(const frag8*)&Sp[wave][t16][32 + quad * 8];
                #pragma unroll
                for (int j = 0; j < 8; ++j) {
                    frag8 bV = *(const frag8*)&Vt[j * 16 + t16][32 + quad * 8];
                    o[j] = __builtin_amdgcn_mfma_f32_16x16x32_bf16(aP1, bV, o[j], 0, 0, 0);
                }
                o9 = __builtin_amdgcn_mfma_f32_16x16x32_bf16(aP1, vONE, o9, 0, 0, 0);
            }
            __builtin_amdgcn_s_setprio(0);
        }
        __syncthreads();
    }

    #pragma unroll
    for (int r = 0; r < 4; ++r) {
        float inv = 1.f / fmaxf(o9[r], 1e-20f);
        int row = qwave + quad * 4 + r;
        #pragma unroll
        for (int j = 0; j < 8; ++j)
            O[(size_t)row * DIM + h * HD + j * 16 + t16] = f2bf(o[j][r] * inv);
    }
}

// ---------------------------------------------------------------------------
// Memory plan:
//  d_ws (41.94 MB, proven):  Qb[4096][2048] | KVb[4096][1024] | Ab[4096][2048]
//    - pre-attn, Ab hosts WqT[2048][2048] + KVT[1024][2048] = contiguous
//      BT[3072][2048] for the fused QKV GEMM
//    - post-attn, KVb hosts WoT[2048][2048] (8.39 MB, exact fit)
//  d_out (33.55 MB fp32):    Xb bf16 [4096][2048] at offset 0 (16.78 MB)
//                            VT  bf16 [512][4096] at +16.78 MB (4.19 MB)
//    both consumed before the final GEMM overwrites d_out.
// ---------------------------------------------------------------------------
extern "C" void kernel_launch(void* const* d_in, const int* in_sizes, int n_in,
                              void* d_out, int out_size, void* d_ws, size_t ws_size,
                              hipStream_t stream)
{
    const float* x  = (const float*)d_in[0];
    const float* fc = (const float*)d_in[2];
    const float* fs = (const float*)d_in[3];
    const float* wq = (const float*)d_in[5];
    const float* wk = (const float*)d_in[6];
    const float* wv = (const float*)d_in[7];
    const float* wo = (const float*)d_in[8];

    ushort* Qb  = (ushort*)d_ws;
    ushort* KVb = Qb + (size_t)SEQ * DIM;
    ushort* Ab  = KVb + (size_t)SEQ * KVLD;
    ushort* WqT = Ab;                                  // overlay (pre-attn)
    ushort* KVT = Ab + (size_t)DIM * DIM;              // overlay (pre-attn)
    ushort* WoT = KVb;                                 // overlay (post-attn)

    ushort* Xb = (ushort*)d_out;                       // bf16 x in d_out scratch
    ushort* VT = Xb + (size_t)SEQ * DIM;               // bf16 V^T [512][4096]

    dim3 blk(256);

    // Convert inputs to bf16 (x flat; weights transposed).
    cvt_kernel<<<(SEQ * DIM) / 2048, blk, 0, stream>>>(x, Xb);
    convT_kernel<<<dim3(DIM / 32, DIM / 32), blk, 0, stream>>>(wq, WqT, DIM, DIM);
    convT_kernel<<<dim3(512 / 32, DIM / 32), blk, 0, stream>>>(wk, KVT, DIM, 512);
    convT_kernel<<<dim3(512 / 32, DIM / 32), blk, 0, stream>>>(
        wv, KVT + (size_t)512 * DIM, DIM, 512);

    // Fused QKV projection (BT = WqT|KVT contiguous at Ab, N=3072).
    gemm_qkv<<<dim3(3072 / 128, SEQ / 128), blk, 0, stream>>>(Xb, Ab, Qb, KVb);

    // RoPE on Q (16 heads, stride DIM, attn scale folded in) and K (4 heads).
    rope_kernel<<<(SEQ * NH * 64) / 256, blk, 0, stream>>>(
        Qb, fc, fs, 4, DIM, 0.08838834764831845f);
    rope_kernel<<<(SEQ * NKV * 64) / 256, blk, 0, stream>>>(
        KVb, fc, fs, 2, KVLD, 1.0f);

    // V^T for coalesced attn staging.
    vtrans_kernel<<<dim3(512 / 32, SEQ / 32), blk, 0, stream>>>(KVb, VT);

    // Flash attention -> Ab (weight overlays consumed). One q-tile per block;
    // grid (NH, 64) so dispatch order is descending-work (see kernel comment).
    attn_kernel<<<dim3(NH, 64), blk, 0, stream>>>(Qb, KVb, VT, Ab);

    // Output projection (WoT overlays KVb; writes fp32 d_out, consuming Xb/VT).
    convT_kernel<<<dim3(DIM / 32, DIM / 32), blk, 0, stream>>>(wo, WoT, DIM, DIM);
    gemm_tn<1><<<dim3(DIM / 128, SEQ / 128), blk, 0, stream>>>(Ab, WoT, d_out, SEQ, DIM, DIM);
}

// Round 5
// 450.878 us; speedup vs baseline: 1.4731x; 1.0042x over previous
//
#include <hip/hip_runtime.h>
#include <hip/hip_bf16.h>
#include <stdint.h>

#define SEQ 4096
#define DIM 2048
#define NH 16
#define NKV 4
#define HD 128
#define KVLD 1024   /* K|V fused row stride in KVb */

// External I/O is FP32 (proven round 2/6); internal tensors bf16.

using frag8 = __attribute__((ext_vector_type(8))) short;
using f32x4 = __attribute__((ext_vector_type(4))) float;

union VecU { ushort u[8]; uint4 v; };

__device__ __forceinline__ float bf2f(ushort u) {
    union { uint32_t u; float f; } v; v.u = ((uint32_t)u) << 16; return v.f;
}
__device__ __forceinline__ ushort f2bf(float f) {
    union { float f; uint32_t u; } v; v.f = f;
    uint32_t r = v.u + 0x7fffu + ((v.u >> 16) & 1u);
    return (ushort)(r >> 16);
}

__device__ __forceinline__ void glds16(const void* g, void* l) {
    __builtin_amdgcn_global_load_lds(
        (const __attribute__((address_space(1))) void*)g,
        (__attribute__((address_space(3))) void*)l, 16, 0, 0);
}

// ---------------------------------------------------------------------------
// fp32 -> bf16 flat convert (8 elems/thread).
// ---------------------------------------------------------------------------
__global__ __launch_bounds__(256) void cvt_kernel(
    const float* __restrict__ src, ushort* __restrict__ dst)
{
    size_t i = ((size_t)blockIdx.x * 256 + threadIdx.x) * 8;
    float4 f0 = *(const float4*)&src[i];
    float4 f1 = *(const float4*)&src[i + 4];
    VecU t;
    t.u[0] = f2bf(f0.x); t.u[1] = f2bf(f0.y); t.u[2] = f2bf(f0.z); t.u[3] = f2bf(f0.w);
    t.u[4] = f2bf(f1.x); t.u[5] = f2bf(f1.y); t.u[6] = f2bf(f1.z); t.u[7] = f2bf(f1.w);
    *(uint4*)&dst[i] = t.v;
}

// ---------------------------------------------------------------------------
// fp32 [K][N] -> bf16 transposed [N][K], 32x32 tiles.
// ---------------------------------------------------------------------------
__global__ __launch_bounds__(256) void convT_kernel(
    const float* __restrict__ src, ushort* __restrict__ dst, int K, int N)
{
    __shared__ ushort T[32][36];
    int r  = threadIdx.x >> 3;
    int c4 = (threadIdx.x & 7) * 4;
    int bk = blockIdx.y * 32, bn = blockIdx.x * 32;
    float4 v = *(const float4*)&src[(size_t)(bk + r) * N + bn + c4];
    T[r][c4]     = f2bf(v.x); T[r][c4 + 1] = f2bf(v.y);
    T[r][c4 + 2] = f2bf(v.z); T[r][c4 + 3] = f2bf(v.w);
    __syncthreads();
    ushort4 o;
    o.x = T[c4][r]; o.y = T[c4 + 1][r]; o.z = T[c4 + 2][r]; o.w = T[c4 + 3][r];
    *(ushort4*)&dst[(size_t)(bn + r) * K + bk + c4] = o;
}

// ---------------------------------------------------------------------------
// bf16 V transpose: KVb[t][512 + d] (ld KVLD) -> VT[d][t] (ld SEQ), 32x32.
// ---------------------------------------------------------------------------
__global__ __launch_bounds__(256) void vtrans_kernel(
    const ushort* __restrict__ src, ushort* __restrict__ dst)
{
    __shared__ ushort T[32][36];
    int r  = threadIdx.x >> 3;
    int c4 = (threadIdx.x & 7) * 4;
    int bt = blockIdx.y * 32, bd = blockIdx.x * 32;   // t-block, d-block
    ushort4 v = *(const ushort4*)&src[(size_t)(bt + r) * KVLD + 512 + bd + c4];
    T[r][c4] = v.x; T[r][c4 + 1] = v.y; T[r][c4 + 2] = v.z; T[r][c4 + 3] = v.w;
    __syncthreads();
    ushort4 o;
    o.x = T[c4][r]; o.y = T[c4 + 1][r]; o.z = T[c4 + 2][r]; o.w = T[c4 + 3][r];
    *(ushort4*)&dst[(size_t)(bd + r) * SEQ + bt + c4] = o;
}

// ---------------------------------------------------------------------------
// m97-style GEMM: C[M][N] = A[M][K] @ BT[N][K]^T, bf16 in; CF: fp32/bf16 out.
// 128x128 tile, BK=32, global_load_lds(16B).
// ---------------------------------------------------------------------------
template <int CF>
__global__ __launch_bounds__(256) void gemm_tn(
    const ushort* __restrict__ A, const ushort* __restrict__ BT,
    void* __restrict__ C, int M, int N, int K)
{
    __shared__ ushort As[128 * 32];
    __shared__ ushort Bs[128 * 32];

    const int tid  = threadIdx.x;
    const int lane = tid & 63;
    const int wave = tid >> 6;
    const int bm   = blockIdx.y * 128;
    const int bn   = blockIdx.x * 128;
    const int wm   = (wave >> 1) * 64;
    const int wn   = (wave & 1) * 64;
    const int quad = lane >> 4;
    const int t16  = lane & 15;
    const int kg   = quad ^ ((t16 >> 1) & 3);

    f32x4 acc[4][4] = {};

    for (int k0 = 0; k0 < K; k0 += 32) {
        #pragma unroll
        for (int it = 0; it < 2; ++it) {
            int gid = it * 256 + tid;
            int r   = gid >> 2;
            int cs  = (gid & 3) ^ ((gid >> 3) & 3);
            glds16(&A[(size_t)(bm + r) * K + k0 + cs * 8],
                   &As[(it * 256 + wave * 64) * 8]);
            glds16(&BT[(size_t)(bn + r) * K + k0 + cs * 8],
                   &Bs[(it * 256 + wave * 64) * 8]);
        }
        __syncthreads();

        frag8 af[4], bf[4];
        #pragma unroll
        for (int i = 0; i < 4; ++i)
            af[i] = *(const frag8*)&As[(wm + i * 16 + t16) * 32 + kg * 8];
        #pragma unroll
        for (int j = 0; j < 4; ++j)
            bf[j] = *(const frag8*)&Bs[(wn + j * 16 + t16) * 32 + kg * 8];
        #pragma unroll
        for (int i = 0; i < 4; ++i)
            #pragma unroll
            for (int j = 0; j < 4; ++j)
                acc[i][j] = __builtin_amdgcn_mfma_f32_16x16x32_bf16(
                    af[i], bf[j], acc[i][j], 0, 0, 0);
        __syncthreads();
    }

    #pragma unroll
    for (int i = 0; i < 4; ++i)
        #pragma unroll
        for (int j = 0; j < 4; ++j)
            #pragma unroll
            for (int r = 0; r < 4; ++r) {
                int row = bm + wm + i * 16 + quad * 4 + r;
                int col = bn + wn + j * 16 + t16;
                if (CF) ((float*)C)[(size_t)row * N + col] = acc[i][j][r];
                else    ((ushort*)C)[(size_t)row * N + col] = f2bf(acc[i][j][r]);
            }
}

// ---------------------------------------------------------------------------
// Fused QKV projection GEMM: A[SEQ][DIM] @ BT[3072][DIM]^T.
// BT rows 0..2047 = WqT, rows 2048..3071 = KVT (wk|wv) — contiguous at Ab.
// Block-uniform C split (2048 is 128-aligned): cols < 2048 -> Qb (ld DIM),
// cols >= 2048 -> KVb (ld KVLD). Grid 24x32 = 768 blocks.
// ---------------------------------------------------------------------------
__global__ __launch_bounds__(256) void gemm_qkv(
    const ushort* __restrict__ A, const ushort* __restrict__ BT,
    ushort* __restrict__ Cq, ushort* __restrict__ Ckv)
{
    const int K = DIM;
    __shared__ ushort As[128 * 32];
    __shared__ ushort Bs[128 * 32];

    const int tid  = threadIdx.x;
    const int lane = tid & 63;
    const int wave = tid >> 6;
    const int bm   = blockIdx.y * 128;
    const int bn   = blockIdx.x * 128;
    const int wm   = (wave >> 1) * 64;
    const int wn   = (wave & 1) * 64;
    const int quad = lane >> 4;
    const int t16  = lane & 15;
    const int kg   = quad ^ ((t16 >> 1) & 3);

    f32x4 acc[4][4] = {};

    for (int k0 = 0; k0 < K; k0 += 32) {
        #pragma unroll
        for (int it = 0; it < 2; ++it) {
            int gid = it * 256 + tid;
            int r   = gid >> 2;
            int cs  = (gid & 3) ^ ((gid >> 3) & 3);
            glds16(&A[(size_t)(bm + r) * K + k0 + cs * 8],
                   &As[(it * 256 + wave * 64) * 8]);
            glds16(&BT[(size_t)(bn + r) * K + k0 + cs * 8],
                   &Bs[(it * 256 + wave * 64) * 8]);
        }
        __syncthreads();

        frag8 af[4], bf[4];
        #pragma unroll
        for (int i = 0; i < 4; ++i)
            af[i] = *(const frag8*)&As[(wm + i * 16 + t16) * 32 + kg * 8];
        #pragma unroll
        for (int j = 0; j < 4; ++j)
            bf[j] = *(const frag8*)&Bs[(wn + j * 16 + t16) * 32 + kg * 8];
        #pragma unroll
        for (int i = 0; i < 4; ++i)
            #pragma unroll
            for (int j = 0; j < 4; ++j)
                acc[i][j] = __builtin_amdgcn_mfma_f32_16x16x32_bf16(
                    af[i], bf[j], acc[i][j], 0, 0, 0);
        __syncthreads();
    }

    // Block-uniform output select.
    ushort* C;
    int ldc, cb;
    if (bn < 2048) { C = Cq;  ldc = DIM;  cb = 0; }
    else           { C = Ckv; ldc = KVLD; cb = 2048; }

    #pragma unroll
    for (int i = 0; i < 4; ++i)
        #pragma unroll
        for (int j = 0; j < 4; ++j)
            #pragma unroll
            for (int r = 0; r < 4; ++r) {
                int row = bm + wm + i * 16 + quad * 4 + r;
                int col = bn + wn + j * 16 + t16;
                C[(size_t)row * ldc + (col - cb)] = f2bf(acc[i][j][r]);
            }
}

// ---------------------------------------------------------------------------
// RoPE in-place on bf16 [SEQ][strideT]; cos/sin fp32. oscale folds the attn
// 1/sqrt(HD) into Q (fp32, pre-quantization -> exact); 1.0 for K.
// ---------------------------------------------------------------------------
__global__ void rope_kernel(ushort* __restrict__ X, const float* __restrict__ Cos,
                            const float* __restrict__ Sin, int log2nh, int strideT,
                            float oscale)
{
    int idx = blockIdx.x * blockDim.x + threadIdx.x;
    int p = idx & 63;
    int h = (idx >> 6) & ((1 << log2nh) - 1);
    int t = idx >> (6 + log2nh);
    size_t base = (size_t)t * strideT + (size_t)h * 128 + 2 * p;
    ushort2 xv = *(ushort2*)&X[base];
    float x1 = bf2f(xv.x), x2 = bf2f(xv.y);
    float c = Cos[t * 64 + p], s = Sin[t * 64 + p];
    ushort2 ov;
    ov.x = f2bf((x1 * c - x2 * s) * oscale);
    ov.y = f2bf((x1 * s + x2 * c) * oscale);
    *(ushort2*)&X[base] = ov;
}

// ---------------------------------------------------------------------------
// Flash attention, causal, GQA, bf16 internal. Grid (NH/2, 64): each block
// processes TWO q-heads (2*hp, 2*hp+1) sharing one kv-head for one 64-row
// q-tile. GQA pairing amortizes LDS traffic: every K/V fragment read from
// LDS feeds BOTH heads' MFMAs (LDS:MFMA ratio 3.3:1 -> 1.9:1 — the round-4
// counters showed the kernel was LDS-pipe-bound). qt = 63 - blockIdx.y so
// dispatch is descending-work (no straggler tail). 512 blocks, 2/CU (54 KB
// LDS); __launch_bounds__(256,2) gives 256-VGPR headroom — NO spill allowed
// (round-2 sentinel: WRITE_SIZE must stay 16 MB).
// Speculative softmax: m inits 0; fast path exps against running m with only
// a lane-LOCAL max trigger test (no shfl chain); full shfl-reduce + rescale +
// Sp rewrite only when __any(lm > m+8) — never for this data, exact for any.
// Row-sum via ones-MFMA (o9). Scores pre-scaled (1/sqrt(HD) in Q via rope).
// T5 setprio around MFMA clusters.
// ---------------------------------------------------------------------------
__global__ __launch_bounds__(256, 2) void attn_kernel(
    const ushort* __restrict__ Q, const ushort* __restrict__ Kb,
    const ushort* __restrict__ VT, ushort* __restrict__ O)
{
    __shared__ ushort Ks[64][136];      // [t][d], padded
    __shared__ ushort Vt[128][72];      // [d][t], padded
    __shared__ ushort Sp[4][32][72];    // per-wave P tiles: rows 0-15 head A, 16-31 head B

    const int tid  = threadIdx.x;
    const int lane = tid & 63;
    const int wave = tid >> 6;
    const int quad = lane >> 4;
    const int t16  = lane & 15;
    const int hp   = blockIdx.x;        // head pair 0..7
    const int hA   = 2 * hp;
    const int hB   = 2 * hp + 1;
    const int kvh  = hp >> 1;

    frag8 vONE;
    #pragma unroll
    for (int i = 0; i < 8; ++i) vONE[i] = (short)0x3F80;   // bf16 1.0

    const int qt = 63 - (int)blockIdx.y;
    const int q0 = qt * 64;
    const int qwave = q0 + wave * 16;
    const int qmaxw = qwave + 15;

    frag8 aQA[4], aQB[4];
    #pragma unroll
    for (int kk = 0; kk < 4; ++kk) {
        aQA[kk] = *(const frag8*)&Q[(size_t)(qwave + t16) * DIM + hA * HD + kk * 32 + quad * 8];
        aQB[kk] = *(const frag8*)&Q[(size_t)(qwave + t16) * DIM + hB * HD + kk * 32 + quad * 8];
    }

    f32x4 oA[8] = {}, oB[8] = {};
    f32x4 o9A = {0.f, 0.f, 0.f, 0.f};
    f32x4 o9B = {0.f, 0.f, 0.f, 0.f};
    float mA[4] = {0.f, 0.f, 0.f, 0.f};
    float mB[4] = {0.f, 0.f, 0.f, 0.f};

    for (int t0 = 0; t0 <= q0 + 63; t0 += 64) {
        // Stage K tile: 64 rows x 128 d (uint4 from fused KVb).
        #pragma unroll
        for (int it = 0; it < 4; ++it) {
            int idx = tid + it * 256;
            int tt  = idx >> 4;
            int c   = (idx & 15) * 8;
            *(uint4*)&Ks[tt][c] =
                *(const uint4*)&Kb[(size_t)(t0 + tt) * KVLD + kvh * HD + c];
        }
        // Stage V^T tile: 128 d x 64 t (uint4 from pre-transposed VT).
        #pragma unroll
        for (int it = 0; it < 4; ++it) {
            int idx = tid + it * 256;
            int d   = idx >> 3;                // 0..127
            int tq  = (idx & 7) * 8;           // 0..56
            *(uint4*)&Vt[d][tq] =
                *(const uint4*)&VT[(size_t)(kvh * HD + d) * SEQ + t0 + tq];
        }
        __syncthreads();

        const bool hi = (t0 + 32 <= qmaxw);    // wave-uniform upper-half guard

        f32x4 sA0 = {0.f,0.f,0.f,0.f}, sA1 = {0.f,0.f,0.f,0.f};
        f32x4 sA2 = {0.f,0.f,0.f,0.f}, sA3 = {0.f,0.f,0.f,0.f};
        f32x4 sB0 = {0.f,0.f,0.f,0.f}, sB1 = {0.f,0.f,0.f,0.f};
        f32x4 sB2 = {0.f,0.f,0.f,0.f}, sB3 = {0.f,0.f,0.f,0.f};

        __builtin_amdgcn_s_setprio(1);
        #pragma unroll
        for (int kk = 0; kk < 4; ++kk) {
            frag8 b0 = *(const frag8*)&Ks[2 * t16][kk * 32 + quad * 8];
            frag8 b1 = *(const frag8*)&Ks[2 * t16 + 1][kk * 32 + quad * 8];
            sA0 = __builtin_amdgcn_mfma_f32_16x16x32_bf16(aQA[kk], b0, sA0, 0, 0, 0);
            sB0 = __builtin_amdgcn_mfma_f32_16x16x32_bf16(aQB[kk], b0, sB0, 0, 0, 0);
            sA1 = __builtin_amdgcn_mfma_f32_16x16x32_bf16(aQA[kk], b1, sA1, 0, 0, 0);
            sB1 = __builtin_amdgcn_mfma_f32_16x16x32_bf16(aQB[kk], b1, sB1, 0, 0, 0);
        }
        if (hi) {
            #pragma unroll
            for (int kk = 0; kk < 4; ++kk) {
                frag8 b2 = *(const frag8*)&Ks[32 + 2 * t16][kk * 32 + quad * 8];
                frag8 b3 = *(const frag8*)&Ks[33 + 2 * t16][kk * 32 + quad * 8];
                sA2 = __builtin_amdgcn_mfma_f32_16x16x32_bf16(aQA[kk], b2, sA2, 0, 0, 0);
                sB2 = __builtin_amdgcn_mfma_f32_16x16x32_bf16(aQB[kk], b2, sB2, 0, 0, 0);
                sA3 = __builtin_amdgcn_mfma_f32_16x16x32_bf16(aQA[kk], b3, sA3, 0, 0, 0);
                sB3 = __builtin_amdgcn_mfma_f32_16x16x32_bf16(aQB[kk], b3, sB3, 0, 0, 0);
            }
        }
        __builtin_amdgcn_s_setprio(0);

        const bool mLo = (t0 + 31 > qwave);        // wave-uniform
        const bool mHi = (t0 + 63 > qwave);

        // Fast path: speculative exp against running m; lane-local trigger.
        bool trig = false;
        #pragma unroll
        for (int r = 0; r < 4; ++r) {
            int q = qwave + quad * 4 + r;
            bool x0 = mLo && (t0 + 2 * t16 > q);
            bool x1 = mLo && (t0 + 2 * t16 + 1 > q);
            bool x2 = mHi && (t0 + 32 + 2 * t16 > q);
            bool x3 = mHi && (t0 + 33 + 2 * t16 > q);
            float vA0 = x0 ? -30000.f : sA0[r];
            float vA1 = x1 ? -30000.f : sA1[r];
            float vA2 = (hi && !x2) ? sA2[r] : -30000.f;
            float vA3 = (hi && !x3) ? sA3[r] : -30000.f;
            float vB0 = x0 ? -30000.f : sB0[r];
            float vB1 = x1 ? -30000.f : sB1[r];
            float vB2 = (hi && !x2) ? sB2[r] : -30000.f;
            float vB3 = (hi && !x3) ? sB3[r] : -30000.f;
            float lmA = fmaxf(fmaxf(vA0, vA1), fmaxf(vA2, vA3));
            float lmB = fmaxf(fmaxf(vB0, vB1), fmaxf(vB2, vB3));
            trig |= (lmA > mA[r] + 8.f) | (lmB > mB[r] + 8.f);
            float eA0 = __expf(vA0 - mA[r]);
            float eA1 = __expf(vA1 - mA[r]);
            float eB0 = __expf(vB0 - mB[r]);
            float eB1 = __expf(vB1 - mB[r]);
            *(uint*)&Sp[wave][quad * 4 + r][2 * t16] =
                (uint)f2bf(eA0) | ((uint)f2bf(eA1) << 16);
            *(uint*)&Sp[wave][16 + quad * 4 + r][2 * t16] =
                (uint)f2bf(eB0) | ((uint)f2bf(eB1) << 16);
            if (hi) {
                float eA2 = __expf(vA2 - mA[r]);
                float eA3 = __expf(vA3 - mA[r]);
                float eB2 = __expf(vB2 - mB[r]);
                float eB3 = __expf(vB3 - mB[r]);
                *(uint*)&Sp[wave][quad * 4 + r][32 + 2 * t16] =
                    (uint)f2bf(eA2) | ((uint)f2bf(eA3) << 16);
                *(uint*)&Sp[wave][16 + quad * 4 + r][32 + 2 * t16] =
                    (uint)f2bf(eB2) | ((uint)f2bf(eB3) << 16);
            }
        }

        // Rare fixup: full cross-lane max, rescale, recompute + rewrite P.
        if (__any(trig)) {
            #pragma unroll
            for (int r = 0; r < 4; ++r) {
                int q = qwave + quad * 4 + r;
                bool x0 = mLo && (t0 + 2 * t16 > q);
                bool x1 = mLo && (t0 + 2 * t16 + 1 > q);
                bool x2 = mHi && (t0 + 32 + 2 * t16 > q);
                bool x3 = mHi && (t0 + 33 + 2 * t16 > q);
                float vA0 = x0 ? -30000.f : sA0[r];
                float vA1 = x1 ? -30000.f : sA1[r];
                float vA2 = (hi && !x2) ? sA2[r] : -30000.f;
                float vA3 = (hi && !x3) ? sA3[r] : -30000.f;
                float vB0 = x0 ? -30000.f : sB0[r];
                float vB1 = x1 ? -30000.f : sB1[r];
                float vB2 = (hi && !x2) ? sB2[r] : -30000.f;
                float vB3 = (hi && !x3) ? sB3[r] : -30000.f;
                float rmA = fmaxf(fmaxf(vA0, vA1), fmaxf(vA2, vA3));
                float rmB = fmaxf(fmaxf(vB0, vB1), fmaxf(vB2, vB3));
                rmA = fmaxf(rmA, __shfl_xor(rmA, 1));
                rmA = fmaxf(rmA, __shfl_xor(rmA, 2));
                rmA = fmaxf(rmA, __shfl_xor(rmA, 4));
                rmA = fmaxf(rmA, __shfl_xor(rmA, 8));
                rmB = fmaxf(rmB, __shfl_xor(rmB, 1));
                rmB = fmaxf(rmB, __shfl_xor(rmB, 2));
                rmB = fmaxf(rmB, __shfl_xor(rmB, 4));
                rmB = fmaxf(rmB, __shfl_xor(rmB, 8));
                float mnA = fmaxf(mA[r], rmA);
                float mnB = fmaxf(mB[r], rmB);
                float alA = __expf(mA[r] - mnA);
                float alB = __expf(mB[r] - mnB);
                #pragma unroll
                for (int j = 0; j < 8; ++j) { oA[j][r] *= alA; oB[j][r] *= alB; }
                o9A[r] *= alA; o9B[r] *= alB;
                mA[r] = mnA; mB[r] = mnB;
                float eA0 = __expf(vA0 - mnA);
                float eA1 = __expf(vA1 - mnA);
                float eB0 = __expf(vB0 - mnB);
                float eB1 = __expf(vB1 - mnB);
                *(uint*)&Sp[wave][quad * 4 + r][2 * t16] =
                    (uint)f2bf(eA0) | ((uint)f2bf(eA1) << 16);
                *(uint*)&Sp[wave][16 + quad * 4 + r][2 * t16] =
                    (uint)f2bf(eB0) | ((uint)f2bf(eB1) << 16);
                if (hi) {
                    float eA2 = __expf(vA2 - mnA);
                    float eA3 = __expf(vA3 - mnA);
                    float eB2 = __expf(vB2 - mnB);
                    float eB3 = __expf(vB3 - mnB);
                    *(uint*)&Sp[wave][quad * 4 + r][32 + 2 * t16] =
                        (uint)f2bf(eA2) | ((uint)f2bf(eA3) << 16);
                    *(uint*)&Sp[wave][16 + quad * 4 + r][32 + 2 * t16] =
                        (uint)f2bf(eB2) | ((uint)f2bf(eB3) << 16);
                }
            }
        }

        frag8 aPA0 = *(const frag8*)&Sp[wave][t16][quad * 8];
        frag8 aPB0 = *(const frag8*)&Sp[wave][16 + t16][quad * 8];
        __builtin_amdgcn_s_setprio(1);
        #pragma unroll
        for (int j = 0; j < 8; ++j) {
            frag8 bV = *(const frag8*)&Vt[j * 16 + t16][quad * 8];
            oA[j] = __builtin_amdgcn_mfma_f32_16x16x32_bf16(aPA0, bV, oA[j], 0, 0, 0);
            oB[j] = __builtin_amdgcn_mfma_f32_16x16x32_bf16(aPB0, bV, oB[j], 0, 0, 0);
        }
        o9A = __builtin_amdgcn_mfma_f32_16x16x32_bf16(aPA0, vONE, o9A, 0, 0, 0);
        o9B = __builtin_amdgcn_mfma_f32_16x16x32_bf16(aPB0, vONE, o9B, 0, 0, 0);
        if (hi) {
            frag8 aPA1 = *(const frag8*)&Sp[wave][t16][32 + quad * 8];
            frag8 aPB1 = *(const frag8*)&Sp[wave][16 + t16][32 + quad * 8];
            #pragma unroll
            for (int j = 0; j < 8; ++j) {
                frag8 bV = *(const frag8*)&Vt[j * 16 + t16][32 + quad * 8];
                oA[j] = __builtin_amdgcn_mfma_f32_16x16x32_bf16(aPA1, bV, oA[j], 0, 0, 0);
                oB[j] = __builtin_amdgcn_mfma_f32_16x16x32_bf16(aPB1, bV, oB[j], 0, 0, 0);
            }
            o9A = __builtin_amdgcn_mfma_f32_16x16x32_bf16(aPA1, vONE, o9A, 0, 0, 0);
            o9B = __builtin_amdgcn_mfma_f32_16x16x32_bf16(aPB1, vONE, o9B, 0, 0, 0);
        }
        __builtin_amdgcn_s_setprio(0);
        __syncthreads();
    }

    #pragma unroll
    for (int r = 0; r < 4; ++r) {
        float invA = 1.f / fmaxf(o9A[r], 1e-20f);
        float invB = 1.f / fmaxf(o9B[r], 1e-20f);
        int row = qwave + quad * 4 + r;
        #pragma unroll
        for (int j = 0; j < 8; ++j) {
            O[(size_t)row * DIM + hA * HD + j * 16 + t16] = f2bf(oA[j][r] * invA);
            O[(size_t)row * DIM + hB * HD + j * 16 + t16] = f2bf(oB[j][r] * invB);
        }
    }
}

// ---------------------------------------------------------------------------
// Memory plan:
//  d_ws (41.94 MB, proven):  Qb[4096][2048] | KVb[4096][1024] | Ab[4096][2048]
//    - pre-attn, Ab hosts WqT[2048][2048] + KVT[1024][2048] = contiguous
//      BT[3072][2048] for the fused QKV GEMM
//    - post-attn, KVb hosts WoT[2048][2048] (8.39 MB, exact fit)
//  d_out (33.55 MB fp32):    Xb bf16 [4096][2048] at offset 0 (16.78 MB)
//                            VT  bf16 [512][4096] at +16.78 MB (4.19 MB)
//    both consumed before the final GEMM overwrites d_out.
// ---------------------------------------------------------------------------
extern "C" void kernel_launch(void* const* d_in, const int* in_sizes, int n_in,
                              void* d_out, int out_size, void* d_ws, size_t ws_size,
                              hipStream_t stream)
{
    const float* x  = (const float*)d_in[0];
    const float* fc = (const float*)d_in[2];
    const float* fs = (const float*)d_in[3];
    const float* wq = (const float*)d_in[5];
    const float* wk = (const float*)d_in[6];
    const float* wv = (const float*)d_in[7];
    const float* wo = (const float*)d_in[8];

    ushort* Qb  = (ushort*)d_ws;
    ushort* KVb = Qb + (size_t)SEQ * DIM;
    ushort* Ab  = KVb + (size_t)SEQ * KVLD;
    ushort* WqT = Ab;                                  // overlay (pre-attn)
    ushort* KVT = Ab + (size_t)DIM * DIM;              // overlay (pre-attn)
    ushort* WoT = KVb;                                 // overlay (post-attn)

    ushort* Xb = (ushort*)d_out;                       // bf16 x in d_out scratch
    ushort* VT = Xb + (size_t)SEQ * DIM;               // bf16 V^T [512][4096]

    dim3 blk(256);

    // Convert inputs to bf16 (x flat; weights transposed).
    cvt_kernel<<<(SEQ * DIM) / 2048, blk, 0, stream>>>(x, Xb);
    convT_kernel<<<dim3(DIM / 32, DIM / 32), blk, 0, stream>>>(wq, WqT, DIM, DIM);
    convT_kernel<<<dim3(512 / 32, DIM / 32), blk, 0, stream>>>(wk, KVT, DIM, 512);
    convT_kernel<<<dim3(512 / 32, DIM / 32), blk, 0, stream>>>(
        wv, KVT + (size_t)512 * DIM, DIM, 512);

    // Fused QKV projection (BT = WqT|KVT contiguous at Ab, N=3072).
    gemm_qkv<<<dim3(3072 / 128, SEQ / 128), blk, 0, stream>>>(Xb, Ab, Qb, KVb);

    // RoPE on Q (16 heads, stride DIM, attn scale folded in) and K (4 heads).
    rope_kernel<<<(SEQ * NH * 64) / 256, blk, 0, stream>>>(
        Qb, fc, fs, 4, DIM, 0.08838834764831845f);
    rope_kernel<<<(SEQ * NKV * 64) / 256, blk, 0, stream>>>(
        KVb, fc, fs, 2, KVLD, 1.0f);

    // V^T for coalesced attn staging.
    vtrans_kernel<<<dim3(512 / 32, SEQ / 32), blk, 0, stream>>>(KVb, VT);

    // Flash attention -> Ab. Head-paired GQA blocks: grid (NH/2, 64),
    // descending-work dispatch (see kernel comment).
    attn_kernel<<<dim3(NH / 2, 64), blk, 0, stream>>>(Qb, KVb, VT, Ab);

    // Output projection (WoT overlays KVb; writes fp32 d_out, consuming Xb/VT).
    convT_kernel<<<dim3(DIM / 32, DIM / 32), blk, 0, stream>>>(wo, WoT, DIM, DIM);
    gemm_tn<1><<<dim3(DIM / 128, SEQ / 128), blk, 0, stream>>>(Ab, WoT, d_out, SEQ, DIM, DIM);
}